// Round 5
// baseline (10795.836 us; speedup 1.0000x reference)
//
#include <hip/hip_runtime.h>
#include <stdint.h>

// Problem constants (match reference)
#define B 128
#define S 256
#define T 256
#define EMBED 256
#define ENC 256
#define DEC 512
#define DOF 4

typedef __attribute__((ext_vector_type(8))) short bf16x8;   // 8 bf16 = 4 VGPRs (MFMA A/B frag)
typedef __attribute__((ext_vector_type(4))) float f32x4;    // MFMA C/D frag

static __device__ __forceinline__ float bf2f(unsigned short u){
  union{uint32_t u;float f;}c; c.u = ((uint32_t)u)<<16; return c.f;
}
static __device__ __forceinline__ unsigned short f2bf(float f){
  union{float f;uint32_t u;}c; c.f=f; uint32_t u=c.u;
  u += 0x7fffu + ((u>>16)&1u);  // round-to-nearest-even
  return (unsigned short)(u>>16);
}
static __device__ __forceinline__ void unp2(uint32_t w, float&a, float&b){
  union{uint32_t u;float f;}c1,c2; c1.u = w<<16; c2.u = w & 0xffff0000u; a=c1.f; b=c2.f;
}
static __device__ __forceinline__ float sigm(float x){ return 1.0f/(1.0f+__expf(-x)); }

// ---------------------------------------------------------------------------
// Coherent (agent-scope, cache-bypassing) accessors for cross-block state.
// Read-only data (weights, encOut, proj, win, emb) uses NORMAL cached loads.
// ---------------------------------------------------------------------------
static __device__ __forceinline__ unsigned long long ldc8(const void* p){
  return __hip_atomic_load((unsigned long long*)p, __ATOMIC_RELAXED, __HIP_MEMORY_SCOPE_AGENT);
}
static __device__ __forceinline__ void stc8(void* p, unsigned long long v){
  __hip_atomic_store((unsigned long long*)p, v, __ATOMIC_RELAXED, __HIP_MEMORY_SCOPE_AGENT);
}
static __device__ __forceinline__ void stc4(void* p, unsigned v){
  __hip_atomic_store((unsigned*)p, v, __ATOMIC_RELAXED, __HIP_MEMORY_SCOPE_AGENT);
}
static __device__ __forceinline__ void stc4f(float* p, float v){
  __hip_atomic_store((unsigned*)p, __float_as_uint(v), __ATOMIC_RELAXED, __HIP_MEMORY_SCOPE_AGENT);
}
static __device__ __forceinline__ float ldc4f(const float* p){
  return __uint_as_float(__hip_atomic_load((const unsigned*)p, __ATOMIC_RELAXED, __HIP_MEMORY_SCOPE_AGENT));
}
union F16x8 { unsigned long long q[2]; bf16x8 v; unsigned short s[8]; };
union Ubf   { bf16x8 v; uint32_t u[4]; unsigned short s[8]; };
static __device__ __forceinline__ bf16x8 ldfrag_c(const unsigned short* p){
  F16x8 u; u.q[0] = ldc8(p); u.q[1] = ldc8(p + 4); return u.v;
}
static __device__ __forceinline__ unsigned long long pack4bf(float a,float b,float c,float d){
  return (unsigned long long)f2bf(a) | ((unsigned long long)f2bf(b)<<16)
       | ((unsigned long long)f2bf(c)<<32) | ((unsigned long long)f2bf(d)<<48);
}

// ---------------------------------------------------------------------------
// Spread-counter device barriers.
// A: 64 lines x 4 arrivals/step.  C: 64 lines x 4.  F: 64 lines x 1 (one line
// per feed block; fm=0 -> lines 0..31, fm=1 -> 32..63).  PAIR: 1 line/batch.
// ---------------------------------------------------------------------------
#define CLINE 32   // u32 per counter line (128 B)
#define A_OFF 0
#define C_OFF 64
#define F_OFF 128
#define PAIR_OFF 192
#define ENC_OFF 320
static __device__ __forceinline__ unsigned* cl(unsigned* c, int line){ return c + (size_t)line*CLINE; }

static __device__ __forceinline__ void bar_arr(unsigned* line){
  __builtin_amdgcn_s_waitcnt(0);     // drain this wave's coherent stores
  __syncthreads();                   // all waves drained
  if (threadIdx.x == 0)
    __hip_atomic_fetch_add(line, 1u, __ATOMIC_RELAXED, __HIP_MEMORY_SCOPE_AGENT);
}
static __device__ __forceinline__ void barw(unsigned* set, unsigned target, int mask){
  if (threadIdx.x < 64){
    unsigned* p = set + (size_t)(threadIdx.x & mask)*CLINE;
    while (!__all((int)(__hip_atomic_load(p, __ATOMIC_RELAXED, __HIP_MEMORY_SCOPE_AGENT) >= target)))
      __builtin_amdgcn_s_sleep(1);
  }
  __syncthreads();
  asm volatile("" ::: "memory");
}
static __device__ __forceinline__ void pair_sync(unsigned* line, unsigned target){
  __builtin_amdgcn_s_waitcnt(0);
  __syncthreads();
  if (threadIdx.x == 0){
    __hip_atomic_fetch_add(line, 1u, __ATOMIC_RELAXED, __HIP_MEMORY_SCOPE_AGENT);
    while (__hip_atomic_load(line, __ATOMIC_RELAXED, __HIP_MEMORY_SCOPE_AGENT) < target)
      __builtin_amdgcn_s_sleep(1);
  }
  __syncthreads();
  asm volatile("" ::: "memory");
}

// swizzled LDS index (in shorts) for encS: row s (0..255), 16B-chunk c (0..31)
static __device__ __forceinline__ int enc_idx(int s, int c){
  return s*256 + (((c & 24) | ((c ^ s) & 7)) << 3);
}

// ---------------------------------------------------------------------------
// Persistent bi-LSTM encoder. Grid 256 = dir(2) x mg(2) x ng(64).
// ---------------------------------------------------------------------------
__global__ __launch_bounds__(256,1) void k_encoder(
  const unsigned short* __restrict__ emb,   // (S,B,256)
  const unsigned short* __restrict__ WF, const unsigned short* __restrict__ WB,
  const float* __restrict__ bF, const float* __restrict__ bB,
  unsigned short* __restrict__ hEnc,        // [dir][2][B][256]
  unsigned short* __restrict__ encOut,      // [B][S][512]
  unsigned* __restrict__ cntBase)           // 2 sets of 16 lines
{
  __shared__ __align__(16) unsigned short Ws[16*520];
  __shared__ __align__(16) float Gs[64*17];
  __shared__ float bsh[16];
  const int bid = blockIdx.x;
  const int dir = bid >> 7;
  const int mg  = (bid >> 6) & 1;
  const int ng  = bid & 63;
  const int tid = threadIdx.x;
  const int lane = tid & 63, w = tid >> 6;
  const int l16 = lane & 15, qd = lane >> 4;
  const int m_base = mg * 64;
  unsigned* mycnt = cntBase + (size_t)dir*16*CLINE;
  unsigned* myline = cl(mycnt, bid & 15);

  const unsigned short* Wg = (dir ? WB : WF) + (size_t)ng*16*512;
  for (int i = tid; i < 16*64; i += 256){
    const int r = i >> 6, s = i & 63;
    *(uint4*)&Ws[r*520 + s*8] = *(const uint4*)&Wg[r*512 + s*8];
  }
  if (tid < 16) bsh[tid] = (dir ? bB : bF)[ng*16 + tid];
  float c[4] = {0.f,0.f,0.f,0.f};
  __syncthreads();

  for (int t = 0; t < S; ++t){
    const int tt = dir ? (S-1-t) : t;
    const unsigned short* Ae = emb + ((size_t)tt*B + m_base + w*16 + l16)*256 + qd*8;
    bf16x8 av[8];
#pragma unroll
    for (int ks = 0; ks < 8; ++ks) av[ks] = *(const bf16x8*)(Ae + ks*32);   // prefetch (cached)
    if (t) barw(mycnt, (unsigned)(8u*(unsigned)t), 15);
    const unsigned short* Ah = hEnc + (((size_t)dir*2 + (size_t)(t&1))*B + m_base + w*16 + l16)*256 + qd*8;
    bf16x8 hf[8];
#pragma unroll
    for (int ks = 0; ks < 8; ++ks) hf[ks] = ldfrag_c(Ah + ks*32);
    f32x4 acc = (f32x4){0.f,0.f,0.f,0.f};
#pragma unroll
    for (int ks = 0; ks < 8; ++ks){
      bf16x8 bb = *(const bf16x8*)&Ws[l16*520 + ks*32 + qd*8];
      acc = __builtin_amdgcn_mfma_f32_16x16x32_bf16(av[ks], bb, acc, 0, 0, 0);
    }
#pragma unroll
    for (int ks = 0; ks < 8; ++ks){
      bf16x8 bb = *(const bf16x8*)&Ws[l16*520 + 256 + ks*32 + qd*8];
      acc = __builtin_amdgcn_mfma_f32_16x16x32_bf16(hf[ks], bb, acc, 0, 0, 0);
    }
    __syncthreads();
#pragma unroll
    for (int r = 0; r < 4; ++r)
      Gs[(w*16 + qd*4 + r)*17 + l16] = acc[r];
    __syncthreads();
    if (tid < 64){
      const int bl = tid;
      float hv[4];
#pragma unroll
      for (int u = 0; u < 4; ++u){
        const float gi = Gs[bl*17 + u*4 + 0] + bsh[u*4 + 0];
        const float gf = Gs[bl*17 + u*4 + 1] + bsh[u*4 + 1];
        const float gg = Gs[bl*17 + u*4 + 2] + bsh[u*4 + 2];
        const float go = Gs[bl*17 + u*4 + 3] + bsh[u*4 + 3];
        const float cn = sigm(gf)*c[u] + sigm(gi)*tanhf(gg);
        c[u] = cn;
        hv[u] = sigm(go)*tanhf(cn);
      }
      const int b2 = m_base + bl;
      const unsigned long long hq = pack4bf(hv[0],hv[1],hv[2],hv[3]);
      stc8(&hEnc[(((size_t)dir*2 + (size_t)((t+1)&1))*B + b2)*256 + ng*4], hq);
      *(unsigned long long*)&encOut[((size_t)b2*S + tt)*512 + dir*256 + ng*4] = hq;
    }
    bar_arr(myline);
  }
}

// ---------------------------------------------------------------------------
// proj = encOut @ W_src^T, precomputed once (step-invariant, as in reference).
// Output layout (B, 2, S, 256): d-half-major so decoder blocks load 128 KB
// contiguously. Grid 4096 = mtile(512) x ntile(8); 64x64 per block.
// ---------------------------------------------------------------------------
__global__ __launch_bounds__(256,2) void k_proj(
  const unsigned short* __restrict__ encOut,  // (B*S, 512)
  const unsigned short* __restrict__ WSP,     // swizzled B-frags (n=d, k=e)
  unsigned short* __restrict__ proj)          // (B, 2, S, 256)
{
  const int nb = blockIdx.x & 7;
  const int mt = blockIdx.x >> 3;
  const int tid = threadIdx.x;
  const int lane = tid & 63, w = tid >> 6;
  const int l16 = lane & 15, qd = lane >> 4;
  const int m0 = mt*64 + w*16;
  const unsigned short* Ap = encOut + ((size_t)m0 + l16)*512 + qd*8;
  bf16x8 av[16];
#pragma unroll
  for (int ks = 0; ks < 16; ++ks) av[ks] = *(const bf16x8*)(Ap + ks*32);
  for (int nn = 0; nn < 4; ++nn){
    const int qn = nb*4 + nn;          // 16-wide d group
    const unsigned short* Bq = WSP + (size_t)qn*16*512 + (size_t)lane*8;
    f32x4 acc = (f32x4){0.f,0.f,0.f,0.f};
#pragma unroll
    for (int ks = 0; ks < 16; ++ks){
      bf16x8 bb = *(const bf16x8*)(Bq + (size_t)ks*512);
      acc = __builtin_amdgcn_mfma_f32_16x16x32_bf16(av[ks], bb, acc, 0, 0, 0);
    }
    const int d = qn*16 + l16, dh = d >> 8, dl = d & 255;
#pragma unroll
    for (int r = 0; r < 4; ++r){
      const int m = m0 + qd*4 + r;
      const int bb2 = m >> 8, s = m & 255;
      proj[(((size_t)bb2*2 + dh)*256 + s)*256 + dl] = f2bf(acc[r]);
    }
  }
}

// ---------------------------------------------------------------------------
// Persistent decoder. Grid 256; block i owns (batch b=i>>1, d-half eh=i&1),
// holds proj[b, :, eh*256..+256) swizzled in LDS (128 KB) for all steps, and
// encOut[b, :, eh*256..+256) (128 KB) in REGISTERS (32 bf16x8/thread) — the
// ctx phase reads no global memory at all.
// Per step: [pre: h-part gates] -> Fwait(subset) -> feed-part gates -> barA
//   -> scores(h.proj) partial -> pair -> softmax -> ctx(registers) -> barC
//   -> feed GEMM (h-part pre-waited) -> barF(own line).
// ---------------------------------------------------------------------------
__global__ __launch_bounds__(256,1) void k_decoder(
  const unsigned short* __restrict__ win,    // (T,B,64)
  const unsigned short* __restrict__ WDx,    // swizzled gates weights
  const float* __restrict__ bD,              // 2048 reordered
  const unsigned short* __restrict__ WCx,    // swizzled W_ctx
  const unsigned short* __restrict__ projq,  // (B,2,S,256) precomputed proj
  const unsigned short* __restrict__ encOut, // (B,S,512)
  const int* __restrict__ in_seq,
  const float* __restrict__ Wout, const float* __restrict__ bout,
  unsigned short* __restrict__ hdec,         // [2][B][512]
  unsigned short* __restrict__ feed,         // [B][512]
  unsigned short* __restrict__ ctxb,         // [B][512]
  float* __restrict__ scp,                   // [B][2][256] partial scores
  float* __restrict__ out_main, float* __restrict__ out_attn,
  unsigned* __restrict__ cnts)
{
  __shared__ __align__(16) unsigned short encS[65536];  // 128 KB resident proj tile
  __shared__ __align__(16) float scrf[1600];
  __shared__ float bsh[16];
  const int bid = blockIdx.x;
  const int b  = bid >> 1, eh = bid & 1;
  const int mg = bid & 1, ng = (bid >> 1) & 127;
  const int tid = threadIdx.x;
  const int lane = tid & 63, w = tid >> 6;
  const int l16 = lane & 15, qd = lane >> 4;
  const int m_base = mg*64;

  // ---- init: bias, mask, resident proj tile (LDS) ----
  if (tid < 16) bsh[tid] = bD[ng*16 + tid];
  const int mymask = (in_seq[b*S + tid] == 0);
  {
    const unsigned short* Pq = projq + (((size_t)b*2 + eh)*256)*256;
    for (int i = 0; i < 32; ++i){
      const int s = i*8 + (tid>>5), cc = tid & 31;
      const uint4 v = *(const uint4*)&Pq[(size_t)s*256 + cc*8];
      *(uint4*)&encS[enc_idx(s, cc)] = v;
    }
  }
  // ---- init: encOut e-half tile in REGISTERS for ctx (step-invariant) ----
  // Thread (w, lane): par=lane>>5, cc=lane&31; owns rows w*64+i2*2+par,
  // e-chunk cc — exactly the addresses the ctx loop consumed before.
  bf16x8 ev[32];
  {
    const int cc = lane & 31, par = lane >> 5;
    const unsigned short* Ep = encOut + ((size_t)b*S)*512 + eh*256 + cc*8;
#pragma unroll
    for (int i2 = 0; i2 < 32; ++i2)
      ev[i2] = *(const bf16x8*)(Ep + (size_t)(w*64 + i2*2 + par)*512);
  }
  float c[4] = {0.f,0.f,0.f,0.f};
  __syncthreads();

  for (int t = 0; t < T; ++t){
    // ---------------- phase A: gates + LSTM update ----------------
    const int row = m_base + w*16 + l16;
    const unsigned short* Aw = win  + ((size_t)t*B + row)*64 + qd*8;
    const unsigned short* Af = feed + (size_t)row*512 + qd*8;
    const unsigned short* Ah = hdec + ((size_t)(t&1)*B + row)*512 + qd*8;
    const unsigned short* Bp = WDx + (size_t)ng*34*512 + (size_t)lane*8;
    f32x4 acc = (f32x4){0.f,0.f,0.f,0.f};
    // pre-wait: h-part of gates (h_{t-1} visible since prev barA) — off chain
    {
      bf16x8 hv[16];
#pragma unroll
      for (int i = 0; i < 16; ++i) hv[i] = ldfrag_c(Ah + i*32);
#pragma unroll
      for (int ks = 0; ks < 16; ++ks){
        bf16x8 bb = *(const bf16x8*)(Bp + (size_t)(18+ks)*512);
        acc = __builtin_amdgcn_mfma_f32_16x16x32_bf16(hv[ks], bb, acc, 0, 0, 0);
      }
    }
    // prefetch feed-part weights + win frags (cached) before the wait
    bf16x8 bv0[18];
#pragma unroll
    for (int ks = 0; ks < 18; ++ks) bv0[ks] = *(const bf16x8*)(Bp + (size_t)ks*512);
    bf16x8 a0 = *(const bf16x8*)(Aw);
    bf16x8 a1 = *(const bf16x8*)(Aw + 32);
    // feed_{t-1} ready: even blocks consume rows 0..63 only (fm=0 subset);
    // odd blocks also run outproj on arbitrary row -> wait all 64 F lines.
    if (t){
      if (bid & 1) barw(cl(cnts, F_OFF), (unsigned)t, 63);
      else         barw(cl(cnts, F_OFF), (unsigned)t, 31);
    }
    {
      bf16x8 av[18];
      av[0] = a0; av[1] = a1;
#pragma unroll
      for (int i = 0; i < 16; ++i) av[2+i] = ldfrag_c(Af + i*32);
#pragma unroll
      for (int ks = 0; ks < 18; ++ks)
        acc = __builtin_amdgcn_mfma_f32_16x16x32_bf16(av[ks], bv0[ks], acc, 0, 0, 0);
    }
    __syncthreads();
#pragma unroll
    for (int r = 0; r < 4; ++r)
      scrf[(w*16 + qd*4 + r)*17 + l16] = acc[r];
    __syncthreads();
    if (tid < 64){
      float hv[4];
#pragma unroll
      for (int u = 0; u < 4; ++u){
        const float gi = scrf[tid*17 + u*4 + 0] + bsh[u*4 + 0];
        const float gf = scrf[tid*17 + u*4 + 1] + bsh[u*4 + 1];
        const float gg = scrf[tid*17 + u*4 + 2] + bsh[u*4 + 2];
        const float go = scrf[tid*17 + u*4 + 3] + bsh[u*4 + 3];
        const float cn = sigm(gf)*c[u] + sigm(gi)*tanhf(gg);
        c[u] = cn;
        hv[u] = sigm(go)*tanhf(cn);
      }
      stc8(&hdec[((size_t)((t+1)&1)*B + m_base + tid)*512 + ng*4],
           pack4bf(hv[0],hv[1],hv[2],hv[3]));
    }
    bar_arr(cl(cnts, A_OFF + (bid & 63)));

    // out-projection of feed_{t-1} (odd blocks; overlaps barA stragglers)
    if ((bid & 1) && t > 0){
      const int b2o = bid >> 1;
      const int d = tid >> 6, kk = lane;
      const unsigned short* fp = feed + (size_t)b2o*512 + kk*8;
      F16x8 u; u.q[0] = ldc8(fp); u.q[1] = ldc8(fp + 4);
      const float* wp = Wout + d*512 + kk*8;
      float p = 0.f;
#pragma unroll
      for (int j2 = 0; j2 < 8; ++j2) p += bf2f(u.s[j2]) * wp[j2];
#pragma unroll
      for (int off = 32; off > 0; off >>= 1) p += __shfl_down(p, off, 64);
      if (kk == 0){
        const float v = p + bout[d];
        out_main[((size_t)b2o*T + (t-1))*4 + d] = (d < 3) ? tanhf(v) : fmaxf(v, 0.f);
      }
    }

    // ---------------- attention (all blocks; d-half of batch b) ----------------
    barw(cl(cnts, A_OFF), (unsigned)(4u*(unsigned)(t+1)), 63);   // full h_t visible
    if (tid < 64){
      F16x8 uq; uq.q[0] = ldc8(hdec + ((size_t)((t+1)&1)*B + b)*512 + eh*256 + tid*4);
      scrf[tid*4+0] = bf2f(uq.s[0]); scrf[tid*4+1] = bf2f(uq.s[1]);
      scrf[tid*4+2] = bf2f(uq.s[2]); scrf[tid*4+3] = bf2f(uq.s[3]);
    }
    __syncthreads();
    float sc = 0.f;
#pragma unroll 8
    for (int cix = 0; cix < 32; ++cix){
      Ubf u8; u8.v = *(const bf16x8*)&encS[enc_idx(tid, cix)];
      float f0,f1,f2,f3,f4,f5,f6,f7;
      unp2(u8.u[0],f0,f1); unp2(u8.u[1],f2,f3); unp2(u8.u[2],f4,f5); unp2(u8.u[3],f6,f7);
      const float* qp = &scrf[cix*8];
      sc += f0*qp[0] + f1*qp[1] + f2*qp[2] + f3*qp[3]
          + f4*qp[4] + f5*qp[5] + f6*qp[6] + f7*qp[7];
    }
    stc4f(&scp[((size_t)b*2 + eh)*256 + tid], sc);
    pair_sync(cl(cnts, PAIR_OFF + b), (unsigned)(2u*(unsigned)(t+1)));
    float tot = sc + ldc4f(&scp[((size_t)b*2 + (1-eh))*256 + tid]);
    if (mymask) tot = -1e30f;
    // softmax over 256 s
    float mx = tot;
#pragma unroll
    for (int off = 32; off > 0; off >>= 1) mx = fmaxf(mx, __shfl_xor(mx, off, 64));
    if (lane == 0) scrf[512 + w] = mx;
    __syncthreads();
    mx = fmaxf(fmaxf(scrf[512], scrf[513]), fmaxf(scrf[514], scrf[515]));
    const float e = __expf(tot - mx);
    float l = e;
#pragma unroll
    for (int off = 32; off > 0; off >>= 1) l += __shfl_xor(l, off, 64);
    if (lane == 0) scrf[516 + w] = l;
    __syncthreads();
    l = scrf[516] + scrf[517] + scrf[518] + scrf[519];
    const float aw = e / l;
    scrf[256 + tid] = aw;
    if (eh == 0) __builtin_nontemporal_store(aw, &out_attn[((size_t)b*T + t)*S + tid]);
    __syncthreads();
    // ctx e-half from REGISTERS (ev): wave w covers 64 s rows (2 per iter).
    // Same FMA order as the global-load version -> bitwise identical output.
    {
      float a[8] = {0,0,0,0,0,0,0,0};
      const int cc = lane & 31, par = lane >> 5;
#pragma unroll
      for (int i2 = 0; i2 < 32; ++i2){
        const int srow = w*64 + i2*2 + par;
        const float wgt = scrf[256 + srow];
        Ubf u8; u8.v = ev[i2];
        float f0,f1,f2,f3,f4,f5,f6,f7;
        unp2(u8.u[0],f0,f1); unp2(u8.u[1],f2,f3); unp2(u8.u[2],f4,f5); unp2(u8.u[3],f6,f7);
        a[0]+=wgt*f0; a[1]+=wgt*f1; a[2]+=wgt*f2; a[3]+=wgt*f3;
        a[4]+=wgt*f4; a[5]+=wgt*f5; a[6]+=wgt*f6; a[7]+=wgt*f7;
      }
#pragma unroll
      for (int j2 = 0; j2 < 8; ++j2) a[j2] += __shfl_xor(a[j2], 32, 64);
      if (par == 0){
#pragma unroll
        for (int j2 = 0; j2 < 8; ++j2) scrf[528 + w*256 + cc*8 + j2] = a[j2];
      }
    }
    __syncthreads();
    if (tid < 128){
      const int e2 = tid*2;
      const float s0 = scrf[528+e2]     + scrf[528+256+e2]     + scrf[528+512+e2]     + scrf[528+768+e2];
      const float s1 = scrf[528+e2+1]   + scrf[528+256+e2+1]   + scrf[528+512+e2+1]   + scrf[528+768+e2+1];
      stc4(&ctxb[(size_t)b*512 + eh*256 + e2],
           (unsigned)f2bf(s0) | ((unsigned)f2bf(s1) << 16));
    }
    bar_arr(cl(cnts, C_OFF + (bid & 63)));

    // ---------------- phase F: feed = tanh([h|ctx] @ W_ctx^T) (64 blocks) ----
    if ((bid & 3) == 3){
      const int fblk = bid >> 2, fm = fblk >> 5, fn = fblk & 31;
      const int frow = fm*64 + w*16 + l16;
      const unsigned short* Fh = hdec + ((size_t)((t+1)&1)*B + frow)*512 + qd*8;
      const unsigned short* Fc = ctxb + (size_t)frow*512 + qd*8;
      const unsigned short* Bf = WCx + (size_t)fn*32*512 + (size_t)lane*8;
      f32x4 fa = (f32x4){0.f,0.f,0.f,0.f};
      {   // h-part before ctx-wait (h ready since barA this step)
        bf16x8 av[16];
#pragma unroll
        for (int ks = 0; ks < 16; ++ks) av[ks] = ldfrag_c(Fh + ks*32);
#pragma unroll
        for (int ks = 0; ks < 16; ++ks){
          bf16x8 bb = *(const bf16x8*)(Bf + (size_t)ks*512);
          fa = __builtin_amdgcn_mfma_f32_16x16x32_bf16(av[ks], bb, fa, 0, 0, 0);
        }
      }
      bf16x8 bv2[16];
#pragma unroll
      for (int ks = 0; ks < 16; ++ks) bv2[ks] = *(const bf16x8*)(Bf + (size_t)(16+ks)*512);
      barw(cl(cnts, C_OFF), (unsigned)(4u*(unsigned)(t+1)), 63);
      {
        bf16x8 av[16];
#pragma unroll
        for (int ks = 0; ks < 16; ++ks) av[ks] = ldfrag_c(Fc + ks*32);
#pragma unroll
        for (int ks = 0; ks < 16; ++ks)
          fa = __builtin_amdgcn_mfma_f32_16x16x32_bf16(av[ks], bv2[ks], fa, 0, 0, 0);
      }
      __syncthreads();
#pragma unroll
      for (int r = 0; r < 4; ++r)
        scrf[(w*16 + qd*4 + r)*17 + l16] = tanhf(fa[r]);
      __syncthreads();
      if (tid < 64){
        const int fb = fm*64 + tid;
#pragma unroll
        for (int u = 0; u < 4; ++u)
          stc8(&feed[(size_t)fb*512 + fn*16 + u*4],
               pack4bf(scrf[tid*17+u*4+0], scrf[tid*17+u*4+1],
                       scrf[tid*17+u*4+2], scrf[tid*17+u*4+3]));
      }
      bar_arr(cl(cnts, F_OFF + (bid >> 2)));   // own line: 1 arrival/step
    }
  }
  // final out-projection (feed_255)
  if (bid & 1){
    barw(cl(cnts, F_OFF), 256u, 63);
    const int b2o = bid >> 1;
    const int d = tid >> 6, kk = lane;
    const unsigned short* fp = feed + (size_t)b2o*512 + kk*8;
    F16x8 u; u.q[0] = ldc8(fp); u.q[1] = ldc8(fp + 4);
    const float* wp = Wout + d*512 + kk*8;
    float p = 0.f;
#pragma unroll
    for (int j2 = 0; j2 < 8; ++j2) p += bf2f(u.s[j2]) * wp[j2];
#pragma unroll
    for (int off = 32; off > 0; off >>= 1) p += __shfl_down(p, off, 64);
    if (kk == 0){
      const float v = p + bout[d];
      out_main[((size_t)b2o*T + 255)*4 + d] = (d < 3) ? tanhf(v) : fmaxf(v, 0.f);
    }
  }
}

// ---------------- setup / builder kernels ----------------
__global__ __launch_bounds__(256) void k_build_encw(
  const float* __restrict__ WihF, const float* __restrict__ WhhF,
  const float* __restrict__ WihB, const float* __restrict__ WhhB,
  unsigned short* WF, unsigned short* WB)
{
  const int idx = blockIdx.x*256 + threadIdx.x;     // 2*1024*512
  const int dir = idx >> 19;
  const int i2 = idx & 524287;
  const int row = i2 >> 9, col = i2 & 511;
  const int j = row >> 2, g = row & 3;
  const int orig = g*256 + j;
  const float* Wih = dir ? WihB : WihF;
  const float* Whh = dir ? WhhB : WhhF;
  const float v = (col < 256) ? Wih[orig*256 + col] : Whh[orig*256 + (col-256)];
  (dir ? WB : WF)[i2] = f2bf(v);
}

// gates weights: reorder rows (j*4+g), pad cols to 1088, swizzle to frag order
__global__ __launch_bounds__(256) void k_build_decw(
  const float* __restrict__ Wih, const float* __restrict__ Whh, unsigned short* WDx)
{
  const int idx = blockIdx.x*256 + threadIdx.x;
  if (idx >= 2048*1088) return;
  const int row = idx / 1088, col = idx - row*1088;
  const int j = row >> 2, g = row & 3;
  const int orig = g*512 + j;
  float v;
  if (col < 16)        v = Wih[orig*528 + col];          // w_t part
  else if (col < 64)   v = 0.f;                          // pad
  else if (col < 576)  v = Wih[orig*528 + (col - 48)];   // feed part
  else                 v = Whh[orig*512 + (col - 576)];  // h part
  const int ng = row >> 4, l16 = row & 15;
  const int ks = col >> 5, qdd = (col >> 3) & 3, jj = col & 7;
  WDx[(((size_t)ng*34 + ks)*64 + qdd*16 + l16)*8 + jj] = f2bf(v);
}

__global__ __launch_bounds__(256) void k_build_wcx(
  const float* __restrict__ Wctx, unsigned short* WCx)
{
  const int idx = blockIdx.x*256 + threadIdx.x;     // 512*1024
  const int n = idx >> 10, k = idx & 1023;
  const int fn = n >> 4, l16 = n & 15;
  const int ks = k >> 5, qdd = (k >> 3) & 3, jj = k & 7;
  WCx[(((size_t)fn*32 + ks)*64 + qdd*16 + l16)*8 + jj] = f2bf(Wctx[(size_t)n*1024 + k]);
}

// W_src in B-frag order for proj GEMM: n = d (512), k = e (512)
__global__ __launch_bounds__(256) void k_build_wsp(
  const float* __restrict__ Wsrc, unsigned short* WSP)
{
  const int idx = blockIdx.x*256 + threadIdx.x;     // 512*512
  const int d = idx >> 9, e = idx & 511;
  const int qn = d >> 4, l16 = d & 15;
  const int ks = e >> 5, qdd = (e >> 3) & 3, jj = e & 7;
  WSP[(((size_t)qn*16 + ks)*64 + qdd*16 + l16)*8 + jj] = f2bf(Wsrc[(size_t)d*512 + e]);
}

__global__ __launch_bounds__(256) void k_build_bias(
  const float* __restrict__ ebF, const float* __restrict__ ebB,
  const float* __restrict__ dB, float* bF, float* bB, float* bD)
{
  const int idx = blockIdx.x*256 + threadIdx.x;     // 4096
  if (idx < 1024) bF[idx] = ebF[(idx&3)*256 + (idx>>2)];
  else if (idx < 2048){ const int i = idx-1024; bB[i] = ebB[(i&3)*256 + (i>>2)]; }
  else { const int i = idx-2048; bD[i] = dB[(i&3)*512 + (i>>2)]; }
}

__global__ __launch_bounds__(256) void k_embed(
  const int* __restrict__ in_seq, const float* __restrict__ table, unsigned short* emb)
{
  const int idx = blockIdx.x*256 + threadIdx.x;     // S*B*256, layout (S,B,E)
  const int e = idx & 255, b = (idx >> 8) & 127, s = idx >> 15;
  const int tok = in_seq[b*S + s];
  emb[idx] = f2bf(table[(size_t)tok*256 + e]);
}

__global__ __launch_bounds__(256) void k_win(
  const float* __restrict__ tgt, unsigned short* win)
{
  const int idx = blockIdx.x*256 + threadIdx.x;     // T*B*64, layout (T,B,64)
  const int c = idx & 63, b = (idx >> 6) & 127, t = idx >> 13;
  float v = 0.f;
  if (c < 16){
    const int k = c >> 2, jj = c & 3;
    const int ts = t + k - 4;
    if (ts >= 0) v = tgt[((size_t)b*T + ts)*4 + jj];
  }
  win[idx] = f2bf(v);
}

// ---------------------------------------------------------------------------
extern "C" void kernel_launch(void* const* d_in, const int* in_sizes, int n_in,
                              void* d_out, int out_size, void* d_ws, size_t ws_size,
                              hipStream_t stream)
{
  const int*   in_seq    = (const int*)d_in[0];
  const float* tgt       = (const float*)d_in[1];
  // d_in[2] = lengths (unused by reference)
  const float* embedding = (const float*)d_in[3];
  const float* eWihF = (const float*)d_in[4];
  const float* eWhhF = (const float*)d_in[5];
  const float* ebF   = (const float*)d_in[6];
  const float* eWihB = (const float*)d_in[7];
  const float* eWhhB = (const float*)d_in[8];
  const float* ebB   = (const float*)d_in[9];
  const float* dWih  = (const float*)d_in[10];
  const float* dWhh  = (const float*)d_in[11];
  const float* dB    = (const float*)d_in[12];
  const float* Wsrc  = (const float*)d_in[13];
  const float* Wctx  = (const float*)d_in[14];
  const float* Wout  = (const float*)d_in[15];
  const float* bout  = (const float*)d_in[16];

  char* ws = (char*)d_ws;
  size_t off = 0;
  auto al = [&](size_t bytes)->char*{
    char* p = ws + off; off += (bytes + 255) & ~(size_t)255; return p; };

  // --- state region (zeroed every launch with one memset) ---
  char* stateBase = ws;
  unsigned short* hEnc = (unsigned short*)al(262144);  // [2][2][128][256]
  unsigned short* hdec = (unsigned short*)al(262144);  // [2][128][512]
  unsigned short* feed = (unsigned short*)al(131072);  // [128][512]
  unsigned short* ctxb = (unsigned short*)al(131072);  // [128][512]
  unsigned*       cnts = (unsigned*)al(45056);         // 352 counter lines
  const size_t stateBytes = off;

  // --- persistent-per-launch scratch (fully rewritten each launch) ---
  unsigned short* emb    = (unsigned short*)al(16777216);  // (S,B,256) bf16
  unsigned short* win    = (unsigned short*)al(4194304);   // (T,B,64) bf16
  unsigned short* encOut = (unsigned short*)al(33554432);  // (B,S,512) bf16
  unsigned short* proj   = (unsigned short*)al(33554432);  // (B,2,S,256) bf16
  unsigned short* WF     = (unsigned short*)al(1048576);   // 1024x512
  unsigned short* WB     = (unsigned short*)al(1048576);
  unsigned short* WDx    = (unsigned short*)al(4456448);   // swizzled 2048x1088
  unsigned short* WCx    = (unsigned short*)al(1048576);   // swizzled 512x1024
  unsigned short* WSP    = (unsigned short*)al(524288);    // swizzled 512x512 (proj B)
  float*          scp    = (float*)al(262144);             // [128][2][256]
  float* bFr = (float*)al(4096);
  float* bBr = (float*)al(4096);
  float* bDr = (float*)al(8192);
  (void)ws_size; (void)in_sizes; (void)n_in; (void)out_size;

  float* out_main = (float*)d_out;
  float* out_attn = out_main + (size_t)B*T*DOF;

  const dim3 blk(256);
  k_build_encw <<<4096,  blk, 0, stream>>>(eWihF, eWhhF, eWihB, eWhhB, WF, WB);
  k_build_decw <<<8704,  blk, 0, stream>>>(dWih, dWhh, WDx);
  k_build_wcx  <<<2048,  blk, 0, stream>>>(Wctx, WCx);
  k_build_wsp  <<<1024,  blk, 0, stream>>>(Wsrc, WSP);
  k_build_bias <<<16,    blk, 0, stream>>>(ebF, ebB, dB, bFr, bBr, bDr);
  k_embed      <<<32768, blk, 0, stream>>>(in_seq, embedding, emb);
  k_win        <<<8192,  blk, 0, stream>>>(tgt, win);
  hipMemsetAsync(stateBase, 0, stateBytes, stream);

  // persistent encoder: 256 steps internally
  k_encoder<<<256, blk, 0, stream>>>(emb, WF, WB, bFr, bBr, hEnc, encOut,
                                     cnts + (size_t)ENC_OFF*CLINE);

  // one-shot proj GEMM (step-invariant attention projection)
  k_proj<<<4096, blk, 0, stream>>>(encOut, WSP, proj);

  // persistent decoder: 256 steps internally (proj in LDS, enc tile in VGPRs)
  k_decoder<<<256, blk, 0, stream>>>(win, WDx, bDr, WCx, proj, encOut, in_seq,
                                     Wout, bout, hdec, feed, ctxb, scp,
                                     out_main, out_attn, cnts);
}

// Round 6
// 8888.078 us; speedup vs baseline: 1.2146x; 1.2146x over previous
//
#include <hip/hip_runtime.h>
#include <stdint.h>

// Problem constants (match reference)
#define B 128
#define S 256
#define T 256
#define EMBED 256
#define ENC 256
#define DEC 512
#define DOF 4

typedef __attribute__((ext_vector_type(8))) short bf16x8;   // 8 bf16 = 4 VGPRs (MFMA A/B frag)
typedef __attribute__((ext_vector_type(4))) float f32x4;    // MFMA C/D frag

static __device__ __forceinline__ float bf2f(unsigned short u){
  union{uint32_t u;float f;}c; c.u = ((uint32_t)u)<<16; return c.f;
}
static __device__ __forceinline__ unsigned short f2bf(float f){
  union{float f;uint32_t u;}c; c.f=f; uint32_t u=c.u;
  u += 0x7fffu + ((u>>16)&1u);  // round-to-nearest-even
  return (unsigned short)(u>>16);
}
static __device__ __forceinline__ void unp2(uint32_t w, float&a, float&b){
  union{uint32_t u;float f;}c1,c2; c1.u = w<<16; c2.u = w & 0xffff0000u; a=c1.f; b=c2.f;
}
static __device__ __forceinline__ float sigm(float x){ return 1.0f/(1.0f+__expf(-x)); }

// ---------------------------------------------------------------------------
// Coherent (agent-scope, cache-bypassing) accessors for cross-block state.
// Read-only data (weights, encOut, proj, win, emb) uses NORMAL cached loads.
// ---------------------------------------------------------------------------
static __device__ __forceinline__ unsigned long long ldc8(const void* p){
  return __hip_atomic_load((unsigned long long*)p, __ATOMIC_RELAXED, __HIP_MEMORY_SCOPE_AGENT);
}
static __device__ __forceinline__ void stc8(void* p, unsigned long long v){
  __hip_atomic_store((unsigned long long*)p, v, __ATOMIC_RELAXED, __HIP_MEMORY_SCOPE_AGENT);
}
static __device__ __forceinline__ void stc4(void* p, unsigned v){
  __hip_atomic_store((unsigned*)p, v, __ATOMIC_RELAXED, __HIP_MEMORY_SCOPE_AGENT);
}
static __device__ __forceinline__ void stc4f(float* p, float v){
  __hip_atomic_store((unsigned*)p, __float_as_uint(v), __ATOMIC_RELAXED, __HIP_MEMORY_SCOPE_AGENT);
}
static __device__ __forceinline__ float ldc4f(const float* p){
  return __uint_as_float(__hip_atomic_load((const unsigned*)p, __ATOMIC_RELAXED, __HIP_MEMORY_SCOPE_AGENT));
}
union F16x8 { unsigned long long q[2]; bf16x8 v; unsigned short s[8]; };
union Ubf   { bf16x8 v; uint32_t u[4]; unsigned short s[8]; };
static __device__ __forceinline__ bf16x8 ldfrag_c(const unsigned short* p){
  F16x8 u; u.q[0] = ldc8(p); u.q[1] = ldc8(p + 4); return u.v;
}
static __device__ __forceinline__ unsigned long long pack4bf(float a,float b,float c,float d){
  return (unsigned long long)f2bf(a) | ((unsigned long long)f2bf(b)<<16)
       | ((unsigned long long)f2bf(c)<<32) | ((unsigned long long)f2bf(d)<<48);
}

// ---------------------------------------------------------------------------
// Spread-counter device barriers.
// A: 64 lines x 4 arrivals/step.  C: 64 lines x 4.  F: 64 lines x 1 (one line
// per feed block; fm=0 -> lines 0..31, fm=1 -> 32..63).  PAIR: 1 line/batch.
// ---------------------------------------------------------------------------
#define CLINE 32   // u32 per counter line (128 B)
#define A_OFF 0
#define C_OFF 64
#define F_OFF 128
#define PAIR_OFF 192
#define ENC_OFF 320
static __device__ __forceinline__ unsigned* cl(unsigned* c, int line){ return c + (size_t)line*CLINE; }

static __device__ __forceinline__ void bar_arr(unsigned* line){
  __builtin_amdgcn_s_waitcnt(0);     // drain this wave's coherent stores
  __syncthreads();                   // all waves drained
  if (threadIdx.x == 0)
    __hip_atomic_fetch_add(line, 1u, __ATOMIC_RELAXED, __HIP_MEMORY_SCOPE_AGENT);
}
static __device__ __forceinline__ void barw(unsigned* set, unsigned target, int mask){
  if (threadIdx.x < 64){
    unsigned* p = set + (size_t)(threadIdx.x & mask)*CLINE;
    while (!__all((int)(__hip_atomic_load(p, __ATOMIC_RELAXED, __HIP_MEMORY_SCOPE_AGENT) >= target)))
      __builtin_amdgcn_s_sleep(1);
  }
  __syncthreads();
  asm volatile("" ::: "memory");
}
static __device__ __forceinline__ void pair_sync(unsigned* line, unsigned target){
  __builtin_amdgcn_s_waitcnt(0);
  __syncthreads();
  if (threadIdx.x == 0){
    __hip_atomic_fetch_add(line, 1u, __ATOMIC_RELAXED, __HIP_MEMORY_SCOPE_AGENT);
    while (__hip_atomic_load(line, __ATOMIC_RELAXED, __HIP_MEMORY_SCOPE_AGENT) < target)
      __builtin_amdgcn_s_sleep(1);
  }
  __syncthreads();
  asm volatile("" ::: "memory");
}

// swizzled LDS index (in shorts) for encS: row s (0..255), 16B-chunk c (0..31)
static __device__ __forceinline__ int enc_idx(int s, int c){
  return s*256 + (((c & 24) | ((c ^ s) & 7)) << 3);
}

// ---------------------------------------------------------------------------
// Persistent bi-LSTM encoder. Grid 256 = dir(2) x mg(2) x ng(64).
// ---------------------------------------------------------------------------
__global__ __launch_bounds__(256,1) void k_encoder(
  const unsigned short* __restrict__ emb,   // (S,B,256)
  const unsigned short* __restrict__ WF, const unsigned short* __restrict__ WB,
  const float* __restrict__ bF, const float* __restrict__ bB,
  unsigned short* __restrict__ hEnc,        // [dir][2][B][256]
  unsigned short* __restrict__ encOut,      // [B][S][512]
  unsigned* __restrict__ cntBase)           // 2 sets of 16 lines
{
  __shared__ __align__(16) unsigned short Ws[16*520];
  __shared__ __align__(16) float Gs[64*17];
  __shared__ float bsh[16];
  const int bid = blockIdx.x;
  const int dir = bid >> 7;
  const int mg  = (bid >> 6) & 1;
  const int ng  = bid & 63;
  const int tid = threadIdx.x;
  const int lane = tid & 63, w = tid >> 6;
  const int l16 = lane & 15, qd = lane >> 4;
  const int m_base = mg * 64;
  unsigned* mycnt = cntBase + (size_t)dir*16*CLINE;
  unsigned* myline = cl(mycnt, bid & 15);

  const unsigned short* Wg = (dir ? WB : WF) + (size_t)ng*16*512;
  for (int i = tid; i < 16*64; i += 256){
    const int r = i >> 6, s = i & 63;
    *(uint4*)&Ws[r*520 + s*8] = *(const uint4*)&Wg[r*512 + s*8];
  }
  if (tid < 16) bsh[tid] = (dir ? bB : bF)[ng*16 + tid];
  float c[4] = {0.f,0.f,0.f,0.f};
  __syncthreads();

  for (int t = 0; t < S; ++t){
    const int tt = dir ? (S-1-t) : t;
    const unsigned short* Ae = emb + ((size_t)tt*B + m_base + w*16 + l16)*256 + qd*8;
    bf16x8 av[8];
#pragma unroll
    for (int ks = 0; ks < 8; ++ks) av[ks] = *(const bf16x8*)(Ae + ks*32);   // prefetch (cached)
    if (t) barw(mycnt, (unsigned)(8u*(unsigned)t), 15);
    const unsigned short* Ah = hEnc + (((size_t)dir*2 + (size_t)(t&1))*B + m_base + w*16 + l16)*256 + qd*8;
    bf16x8 hf[8];
#pragma unroll
    for (int ks = 0; ks < 8; ++ks) hf[ks] = ldfrag_c(Ah + ks*32);
    f32x4 acc = (f32x4){0.f,0.f,0.f,0.f};
#pragma unroll
    for (int ks = 0; ks < 8; ++ks){
      bf16x8 bb = *(const bf16x8*)&Ws[l16*520 + ks*32 + qd*8];
      acc = __builtin_amdgcn_mfma_f32_16x16x32_bf16(av[ks], bb, acc, 0, 0, 0);
    }
#pragma unroll
    for (int ks = 0; ks < 8; ++ks){
      bf16x8 bb = *(const bf16x8*)&Ws[l16*520 + 256 + ks*32 + qd*8];
      acc = __builtin_amdgcn_mfma_f32_16x16x32_bf16(hf[ks], bb, acc, 0, 0, 0);
    }
    __syncthreads();
#pragma unroll
    for (int r = 0; r < 4; ++r)
      Gs[(w*16 + qd*4 + r)*17 + l16] = acc[r];
    __syncthreads();
    if (tid < 64){
      const int bl = tid;
      float hv[4];
#pragma unroll
      for (int u = 0; u < 4; ++u){
        const float gi = Gs[bl*17 + u*4 + 0] + bsh[u*4 + 0];
        const float gf = Gs[bl*17 + u*4 + 1] + bsh[u*4 + 1];
        const float gg = Gs[bl*17 + u*4 + 2] + bsh[u*4 + 2];
        const float go = Gs[bl*17 + u*4 + 3] + bsh[u*4 + 3];
        const float cn = sigm(gf)*c[u] + sigm(gi)*tanhf(gg);
        c[u] = cn;
        hv[u] = sigm(go)*tanhf(cn);
      }
      const int b2 = m_base + bl;
      const unsigned long long hq = pack4bf(hv[0],hv[1],hv[2],hv[3]);
      stc8(&hEnc[(((size_t)dir*2 + (size_t)((t+1)&1))*B + b2)*256 + ng*4], hq);
      *(unsigned long long*)&encOut[((size_t)b2*S + tt)*512 + dir*256 + ng*4] = hq;
    }
    bar_arr(myline);
  }
}

// ---------------------------------------------------------------------------
// proj = encOut @ W_src^T, precomputed once (step-invariant, as in reference).
// Output layout (B, 2, S, 256): d-half-major so decoder blocks load 128 KB
// contiguously. Grid 4096 = mtile(512) x ntile(8); 64x64 per block.
// ---------------------------------------------------------------------------
__global__ __launch_bounds__(256,2) void k_proj(
  const unsigned short* __restrict__ encOut,  // (B*S, 512)
  const unsigned short* __restrict__ WSP,     // swizzled B-frags (n=d, k=e)
  unsigned short* __restrict__ proj)          // (B, 2, S, 256)
{
  const int nb = blockIdx.x & 7;
  const int mt = blockIdx.x >> 3;
  const int tid = threadIdx.x;
  const int lane = tid & 63, w = tid >> 6;
  const int l16 = lane & 15, qd = lane >> 4;
  const int m0 = mt*64 + w*16;
  const unsigned short* Ap = encOut + ((size_t)m0 + l16)*512 + qd*8;
  bf16x8 av[16];
#pragma unroll
  for (int ks = 0; ks < 16; ++ks) av[ks] = *(const bf16x8*)(Ap + ks*32);
  for (int nn = 0; nn < 4; ++nn){
    const int qn = nb*4 + nn;          // 16-wide d group
    const unsigned short* Bq = WSP + (size_t)qn*16*512 + (size_t)lane*8;
    f32x4 acc = (f32x4){0.f,0.f,0.f,0.f};
#pragma unroll
    for (int ks = 0; ks < 16; ++ks){
      bf16x8 bb = *(const bf16x8*)(Bq + (size_t)ks*512);
      acc = __builtin_amdgcn_mfma_f32_16x16x32_bf16(av[ks], bb, acc, 0, 0, 0);
    }
    const int d = qn*16 + l16, dh = d >> 8, dl = d & 255;
#pragma unroll
    for (int r = 0; r < 4; ++r){
      const int m = m0 + qd*4 + r;
      const int bb2 = m >> 8, s = m & 255;
      proj[(((size_t)bb2*2 + dh)*256 + s)*256 + dl] = f2bf(acc[r]);
    }
  }
}

// ---------------------------------------------------------------------------
// Persistent decoder. Grid 256; block i owns (batch b=i>>1, d-half eh=i&1),
// holds proj[b, :, eh*256..+256) swizzled in LDS (128 KB) for all steps, and
// encOut[b, :, eh*256..+256) (128 KB) in REGISTERS (ev[32], 128 VGPR) — the
// ctx phase reads no global memory. All MFMA phases are CHUNKED (8 frags at
// a time) to keep transient register peaks under the 256-VGPR budget; the
// accumulation order is unchanged (bitwise-identical results).
// Per step: [pre: h-part gates] -> Fwait(subset) -> w_t+feed gates -> barA
//   -> scores(h.proj) partial -> pair -> softmax -> ctx(registers) -> barC
//   -> feed GEMM (h-part pre-waited) -> barF(own line).
// ---------------------------------------------------------------------------
__global__ __launch_bounds__(256,1) void k_decoder(
  const unsigned short* __restrict__ win,    // (T,B,64)
  const unsigned short* __restrict__ WDx,    // swizzled gates weights
  const float* __restrict__ bD,              // 2048 reordered
  const unsigned short* __restrict__ WCx,    // swizzled W_ctx
  const unsigned short* __restrict__ projq,  // (B,2,S,256) precomputed proj
  const unsigned short* __restrict__ encOut, // (B,S,512)
  const int* __restrict__ in_seq,
  const float* __restrict__ Wout, const float* __restrict__ bout,
  unsigned short* __restrict__ hdec,         // [2][B][512]
  unsigned short* __restrict__ feed,         // [B][512]
  unsigned short* __restrict__ ctxb,         // [B][512]
  float* __restrict__ scp,                   // [B][2][256] partial scores
  float* __restrict__ out_main, float* __restrict__ out_attn,
  unsigned* __restrict__ cnts)
{
  __shared__ __align__(16) unsigned short encS[65536];  // 128 KB resident proj tile
  __shared__ __align__(16) float scrf[1600];
  __shared__ float bsh[16];
  const int bid = blockIdx.x;
  const int b  = bid >> 1, eh = bid & 1;
  const int mg = bid & 1, ng = (bid >> 1) & 127;
  const int tid = threadIdx.x;
  const int lane = tid & 63, w = tid >> 6;
  const int l16 = lane & 15, qd = lane >> 4;
  const int m_base = mg*64;

  // ---- init: bias, mask, resident proj tile (LDS) ----
  if (tid < 16) bsh[tid] = bD[ng*16 + tid];
  const int mymask = (in_seq[b*S + tid] == 0);
  {
    const unsigned short* Pq = projq + (((size_t)b*2 + eh)*256)*256;
    for (int i = 0; i < 32; ++i){
      const int s = i*8 + (tid>>5), cc = tid & 31;
      const uint4 v = *(const uint4*)&Pq[(size_t)s*256 + cc*8];
      *(uint4*)&encS[enc_idx(s, cc)] = v;
    }
  }
  // ---- init: encOut e-half tile in REGISTERS for ctx (step-invariant) ----
  bf16x8 ev[32];
  {
    const int cc = lane & 31, par = lane >> 5;
    const unsigned short* Ep = encOut + ((size_t)b*S)*512 + eh*256 + cc*8;
#pragma unroll
    for (int i2 = 0; i2 < 32; ++i2)
      ev[i2] = *(const bf16x8*)(Ep + (size_t)(w*64 + i2*2 + par)*512);
  }
  float c[4] = {0.f,0.f,0.f,0.f};
  __syncthreads();

  for (int t = 0; t < T; ++t){
    // ---------------- phase A: gates + LSTM update (chunked MFMA) ----------
    const int row = m_base + w*16 + l16;
    const unsigned short* Aw = win  + ((size_t)t*B + row)*64 + qd*8;
    const unsigned short* Af = feed + (size_t)row*512 + qd*8;
    const unsigned short* Ah = hdec + ((size_t)(t&1)*B + row)*512 + qd*8;
    const unsigned short* Bp = WDx + (size_t)ng*34*512 + (size_t)lane*8;
    f32x4 acc = (f32x4){0.f,0.f,0.f,0.f};
    // pre-wait: h-part of gates (h_{t-1} visible since prev barA) — off chain
#pragma unroll
    for (int ch = 0; ch < 2; ++ch){
      bf16x8 hv[8];
#pragma unroll
      for (int i = 0; i < 8; ++i) hv[i] = ldfrag_c(Ah + (ch*8 + i)*32);
#pragma unroll
      for (int ks = 0; ks < 8; ++ks){
        bf16x8 bb = *(const bf16x8*)(Bp + (size_t)(18 + ch*8 + ks)*512);
        acc = __builtin_amdgcn_mfma_f32_16x16x32_bf16(hv[ks], bb, acc, 0, 0, 0);
      }
    }
    // prefetch win frags (8 regs) before the wait
    bf16x8 a0 = *(const bf16x8*)(Aw);
    bf16x8 a1 = *(const bf16x8*)(Aw + 32);
    // feed_{t-1} ready: even blocks consume rows 0..63 only (fm=0 subset);
    // odd blocks also run outproj on arbitrary row -> wait all 64 F lines.
    if (t){
      if (bid & 1) barw(cl(cnts, F_OFF), (unsigned)t, 63);
      else         barw(cl(cnts, F_OFF), (unsigned)t, 31);
    }
    {   // w_t part (order: bv0[0], bv0[1] as before)
      bf16x8 b0 = *(const bf16x8*)(Bp);
      bf16x8 b1 = *(const bf16x8*)(Bp + 512);
      acc = __builtin_amdgcn_mfma_f32_16x16x32_bf16(a0, b0, acc, 0, 0, 0);
      acc = __builtin_amdgcn_mfma_f32_16x16x32_bf16(a1, b1, acc, 0, 0, 0);
    }
#pragma unroll
    for (int ch = 0; ch < 2; ++ch){   // feed part, chunks of 8
      bf16x8 av[8], bv[8];
#pragma unroll
      for (int i = 0; i < 8; ++i){
        av[i] = ldfrag_c(Af + (ch*8 + i)*32);
        bv[i] = *(const bf16x8*)(Bp + (size_t)(2 + ch*8 + i)*512);
      }
#pragma unroll
      for (int ks = 0; ks < 8; ++ks)
        acc = __builtin_amdgcn_mfma_f32_16x16x32_bf16(av[ks], bv[ks], acc, 0, 0, 0);
    }
    __syncthreads();
#pragma unroll
    for (int r = 0; r < 4; ++r)
      scrf[(w*16 + qd*4 + r)*17 + l16] = acc[r];
    __syncthreads();
    if (tid < 64){
      float hv[4];
#pragma unroll
      for (int u = 0; u < 4; ++u){
        const float gi = scrf[tid*17 + u*4 + 0] + bsh[u*4 + 0];
        const float gf = scrf[tid*17 + u*4 + 1] + bsh[u*4 + 1];
        const float gg = scrf[tid*17 + u*4 + 2] + bsh[u*4 + 2];
        const float go = scrf[tid*17 + u*4 + 3] + bsh[u*4 + 3];
        const float cn = sigm(gf)*c[u] + sigm(gi)*tanhf(gg);
        c[u] = cn;
        hv[u] = sigm(go)*tanhf(cn);
      }
      stc8(&hdec[((size_t)((t+1)&1)*B + m_base + tid)*512 + ng*4],
           pack4bf(hv[0],hv[1],hv[2],hv[3]));
    }
    bar_arr(cl(cnts, A_OFF + (bid & 63)));

    // out-projection of feed_{t-1} (odd blocks; overlaps barA stragglers)
    if ((bid & 1) && t > 0){
      const int b2o = bid >> 1;
      const int d = tid >> 6, kk = lane;
      const unsigned short* fp = feed + (size_t)b2o*512 + kk*8;
      F16x8 u; u.q[0] = ldc8(fp); u.q[1] = ldc8(fp + 4);
      const float* wp = Wout + d*512 + kk*8;
      float p = 0.f;
#pragma unroll
      for (int j2 = 0; j2 < 8; ++j2) p += bf2f(u.s[j2]) * wp[j2];
#pragma unroll
      for (int off = 32; off > 0; off >>= 1) p += __shfl_down(p, off, 64);
      if (kk == 0){
        const float v = p + bout[d];
        out_main[((size_t)b2o*T + (t-1))*4 + d] = (d < 3) ? tanhf(v) : fmaxf(v, 0.f);
      }
    }

    // ---------------- attention (all blocks; d-half of batch b) ----------------
    barw(cl(cnts, A_OFF), (unsigned)(4u*(unsigned)(t+1)), 63);   // full h_t visible
    if (tid < 64){
      F16x8 uq; uq.q[0] = ldc8(hdec + ((size_t)((t+1)&1)*B + b)*512 + eh*256 + tid*4);
      scrf[tid*4+0] = bf2f(uq.s[0]); scrf[tid*4+1] = bf2f(uq.s[1]);
      scrf[tid*4+2] = bf2f(uq.s[2]); scrf[tid*4+3] = bf2f(uq.s[3]);
    }
    __syncthreads();
    float sc = 0.f;
#pragma unroll 8
    for (int cix = 0; cix < 32; ++cix){
      Ubf u8; u8.v = *(const bf16x8*)&encS[enc_idx(tid, cix)];
      float f0,f1,f2,f3,f4,f5,f6,f7;
      unp2(u8.u[0],f0,f1); unp2(u8.u[1],f2,f3); unp2(u8.u[2],f4,f5); unp2(u8.u[3],f6,f7);
      const float* qp = &scrf[cix*8];
      sc += f0*qp[0] + f1*qp[1] + f2*qp[2] + f3*qp[3]
          + f4*qp[4] + f5*qp[5] + f6*qp[6] + f7*qp[7];
    }
    stc4f(&scp[((size_t)b*2 + eh)*256 + tid], sc);
    pair_sync(cl(cnts, PAIR_OFF + b), (unsigned)(2u*(unsigned)(t+1)));
    float tot = sc + ldc4f(&scp[((size_t)b*2 + (1-eh))*256 + tid]);
    if (mymask) tot = -1e30f;
    // softmax over 256 s
    float mx = tot;
#pragma unroll
    for (int off = 32; off > 0; off >>= 1) mx = fmaxf(mx, __shfl_xor(mx, off, 64));
    if (lane == 0) scrf[512 + w] = mx;
    __syncthreads();
    mx = fmaxf(fmaxf(scrf[512], scrf[513]), fmaxf(scrf[514], scrf[515]));
    const float e = __expf(tot - mx);
    float l = e;
#pragma unroll
    for (int off = 32; off > 0; off >>= 1) l += __shfl_xor(l, off, 64);
    if (lane == 0) scrf[516 + w] = l;
    __syncthreads();
    l = scrf[516] + scrf[517] + scrf[518] + scrf[519];
    const float aw = e / l;
    scrf[256 + tid] = aw;
    if (eh == 0) __builtin_nontemporal_store(aw, &out_attn[((size_t)b*T + t)*S + tid]);
    __syncthreads();
    // ctx e-half from REGISTERS (ev): wave w covers 64 s rows (2 per iter).
    // Same FMA order as the global-load version -> bitwise identical output.
    {
      float a[8] = {0,0,0,0,0,0,0,0};
      const int cc = lane & 31, par = lane >> 5;
#pragma unroll
      for (int i2 = 0; i2 < 32; ++i2){
        const int srow = w*64 + i2*2 + par;
        const float wgt = scrf[256 + srow];
        Ubf u8; u8.v = ev[i2];
        float f0,f1,f2,f3,f4,f5,f6,f7;
        unp2(u8.u[0],f0,f1); unp2(u8.u[1],f2,f3); unp2(u8.u[2],f4,f5); unp2(u8.u[3],f6,f7);
        a[0]+=wgt*f0; a[1]+=wgt*f1; a[2]+=wgt*f2; a[3]+=wgt*f3;
        a[4]+=wgt*f4; a[5]+=wgt*f5; a[6]+=wgt*f6; a[7]+=wgt*f7;
      }
#pragma unroll
      for (int j2 = 0; j2 < 8; ++j2) a[j2] += __shfl_xor(a[j2], 32, 64);
      if (par == 0){
#pragma unroll
        for (int j2 = 0; j2 < 8; ++j2) scrf[528 + w*256 + cc*8 + j2] = a[j2];
      }
    }
    __syncthreads();
    if (tid < 128){
      const int e2 = tid*2;
      const float s0 = scrf[528+e2]     + scrf[528+256+e2]     + scrf[528+512+e2]     + scrf[528+768+e2];
      const float s1 = scrf[528+e2+1]   + scrf[528+256+e2+1]   + scrf[528+512+e2+1]   + scrf[528+768+e2+1];
      stc4(&ctxb[(size_t)b*512 + eh*256 + e2],
           (unsigned)f2bf(s0) | ((unsigned)f2bf(s1) << 16));
    }
    bar_arr(cl(cnts, C_OFF + (bid & 63)));

    // ---------------- phase F: feed = tanh([h|ctx] @ W_ctx^T) (64 blocks) ----
    if ((bid & 3) == 3){
      const int fblk = bid >> 2, fm = fblk >> 5, fn = fblk & 31;
      const int frow = fm*64 + w*16 + l16;
      const unsigned short* Fh = hdec + ((size_t)((t+1)&1)*B + frow)*512 + qd*8;
      const unsigned short* Fc = ctxb + (size_t)frow*512 + qd*8;
      const unsigned short* Bf = WCx + (size_t)fn*32*512 + (size_t)lane*8;
      f32x4 fa = (f32x4){0.f,0.f,0.f,0.f};
      // h-part before ctx-wait (h ready since barA this step), chunks of 8
#pragma unroll
      for (int ch = 0; ch < 2; ++ch){
        bf16x8 av[8], bv[8];
#pragma unroll
        for (int i = 0; i < 8; ++i){
          av[i] = ldfrag_c(Fh + (ch*8 + i)*32);
          bv[i] = *(const bf16x8*)(Bf + (size_t)(ch*8 + i)*512);
        }
#pragma unroll
        for (int ks = 0; ks < 8; ++ks)
          fa = __builtin_amdgcn_mfma_f32_16x16x32_bf16(av[ks], bv[ks], fa, 0, 0, 0);
      }
      barw(cl(cnts, C_OFF), (unsigned)(4u*(unsigned)(t+1)), 63);
      // ctx part, chunks of 8
#pragma unroll
      for (int ch = 0; ch < 2; ++ch){
        bf16x8 av[8], bv[8];
#pragma unroll
        for (int i = 0; i < 8; ++i){
          av[i] = ldfrag_c(Fc + (ch*8 + i)*32);
          bv[i] = *(const bf16x8*)(Bf + (size_t)(16 + ch*8 + i)*512);
        }
#pragma unroll
        for (int ks = 0; ks < 8; ++ks)
          fa = __builtin_amdgcn_mfma_f32_16x16x32_bf16(av[ks], bv[ks], fa, 0, 0, 0);
      }
      __syncthreads();
#pragma unroll
      for (int r = 0; r < 4; ++r)
        scrf[(w*16 + qd*4 + r)*17 + l16] = tanhf(fa[r]);
      __syncthreads();
      if (tid < 64){
        const int fb = fm*64 + tid;
#pragma unroll
        for (int u = 0; u < 4; ++u)
          stc8(&feed[(size_t)fb*512 + fn*16 + u*4],
               pack4bf(scrf[tid*17+u*4+0], scrf[tid*17+u*4+1],
                       scrf[tid*17+u*4+2], scrf[tid*17+u*4+3]));
      }
      bar_arr(cl(cnts, F_OFF + (bid >> 2)));   // own line: 1 arrival/step
    }
  }
  // final out-projection (feed_255)
  if (bid & 1){
    barw(cl(cnts, F_OFF), 256u, 63);
    const int b2o = bid >> 1;
    const int d = tid >> 6, kk = lane;
    const unsigned short* fp = feed + (size_t)b2o*512 + kk*8;
    F16x8 u; u.q[0] = ldc8(fp); u.q[1] = ldc8(fp + 4);
    const float* wp = Wout + d*512 + kk*8;
    float p = 0.f;
#pragma unroll
    for (int j2 = 0; j2 < 8; ++j2) p += bf2f(u.s[j2]) * wp[j2];
#pragma unroll
    for (int off = 32; off > 0; off >>= 1) p += __shfl_down(p, off, 64);
    if (kk == 0){
      const float v = p + bout[d];
      out_main[((size_t)b2o*T + 255)*4 + d] = (d < 3) ? tanhf(v) : fmaxf(v, 0.f);
    }
  }
}

// ---------------- setup / builder kernels ----------------
__global__ __launch_bounds__(256) void k_build_encw(
  const float* __restrict__ WihF, const float* __restrict__ WhhF,
  const float* __restrict__ WihB, const float* __restrict__ WhhB,
  unsigned short* WF, unsigned short* WB)
{
  const int idx = blockIdx.x*256 + threadIdx.x;     // 2*1024*512
  const int dir = idx >> 19;
  const int i2 = idx & 524287;
  const int row = i2 >> 9, col = i2 & 511;
  const int j = row >> 2, g = row & 3;
  const int orig = g*256 + j;
  const float* Wih = dir ? WihB : WihF;
  const float* Whh = dir ? WhhB : WhhF;
  const float v = (col < 256) ? Wih[orig*256 + col] : Whh[orig*256 + (col-256)];
  (dir ? WB : WF)[i2] = f2bf(v);
}

// gates weights: reorder rows (j*4+g), pad cols to 1088, swizzle to frag order
__global__ __launch_bounds__(256) void k_build_decw(
  const float* __restrict__ Wih, const float* __restrict__ Whh, unsigned short* WDx)
{
  const int idx = blockIdx.x*256 + threadIdx.x;
  if (idx >= 2048*1088) return;
  const int row = idx / 1088, col = idx - row*1088;
  const int j = row >> 2, g = row & 3;
  const int orig = g*512 + j;
  float v;
  if (col < 16)        v = Wih[orig*528 + col];          // w_t part
  else if (col < 64)   v = 0.f;                          // pad
  else if (col < 576)  v = Wih[orig*528 + (col - 48)];   // feed part
  else                 v = Whh[orig*512 + (col - 576)];  // h part
  const int ng = row >> 4, l16 = row & 15;
  const int ks = col >> 5, qdd = (col >> 3) & 3, jj = col & 7;
  WDx[(((size_t)ng*34 + ks)*64 + qdd*16 + l16)*8 + jj] = f2bf(v);
}

__global__ __launch_bounds__(256) void k_build_wcx(
  const float* __restrict__ Wctx, unsigned short* WCx)
{
  const int idx = blockIdx.x*256 + threadIdx.x;     // 512*1024
  const int n = idx >> 10, k = idx & 1023;
  const int fn = n >> 4, l16 = n & 15;
  const int ks = k >> 5, qdd = (k >> 3) & 3, jj = k & 7;
  WCx[(((size_t)fn*32 + ks)*64 + qdd*16 + l16)*8 + jj] = f2bf(Wctx[(size_t)n*1024 + k]);
}

// W_src in B-frag order for proj GEMM: n = d (512), k = e (512)
__global__ __launch_bounds__(256) void k_build_wsp(
  const float* __restrict__ Wsrc, unsigned short* WSP)
{
  const int idx = blockIdx.x*256 + threadIdx.x;     // 512*512
  const int d = idx >> 9, e = idx & 511;
  const int qn = d >> 4, l16 = d & 15;
  const int ks = e >> 5, qdd = (e >> 3) & 3, jj = e & 7;
  WSP[(((size_t)qn*16 + ks)*64 + qdd*16 + l16)*8 + jj] = f2bf(Wsrc[(size_t)d*512 + e]);
}

__global__ __launch_bounds__(256) void k_build_bias(
  const float* __restrict__ ebF, const float* __restrict__ ebB,
  const float* __restrict__ dB, float* bF, float* bB, float* bD)
{
  const int idx = blockIdx.x*256 + threadIdx.x;     // 4096
  if (idx < 1024) bF[idx] = ebF[(idx&3)*256 + (idx>>2)];
  else if (idx < 2048){ const int i = idx-1024; bB[i] = ebB[(i&3)*256 + (i>>2)]; }
  else { const int i = idx-2048; bD[i] = dB[(i&3)*512 + (i>>2)]; }
}

__global__ __launch_bounds__(256) void k_embed(
  const int* __restrict__ in_seq, const float* __restrict__ table, unsigned short* emb)
{
  const int idx = blockIdx.x*256 + threadIdx.x;     // S*B*256, layout (S,B,E)
  const int e = idx & 255, b = (idx >> 8) & 127, s = idx >> 15;
  const int tok = in_seq[b*S + s];
  emb[idx] = f2bf(table[(size_t)tok*256 + e]);
}

__global__ __launch_bounds__(256) void k_win(
  const float* __restrict__ tgt, unsigned short* win)
{
  const int idx = blockIdx.x*256 + threadIdx.x;     // T*B*64, layout (T,B,64)
  const int c = idx & 63, b = (idx >> 6) & 127, t = idx >> 13;
  float v = 0.f;
  if (c < 16){
    const int k = c >> 2, jj = c & 3;
    const int ts = t + k - 4;
    if (ts >= 0) v = tgt[((size_t)b*T + ts)*4 + jj];
  }
  win[idx] = f2bf(v);
}

// ---------------------------------------------------------------------------
extern "C" void kernel_launch(void* const* d_in, const int* in_sizes, int n_in,
                              void* d_out, int out_size, void* d_ws, size_t ws_size,
                              hipStream_t stream)
{
  const int*   in_seq    = (const int*)d_in[0];
  const float* tgt       = (const float*)d_in[1];
  // d_in[2] = lengths (unused by reference)
  const float* embedding = (const float*)d_in[3];
  const float* eWihF = (const float*)d_in[4];
  const float* eWhhF = (const float*)d_in[5];
  const float* ebF   = (const float*)d_in[6];
  const float* eWihB = (const float*)d_in[7];
  const float* eWhhB = (const float*)d_in[8];
  const float* ebB   = (const float*)d_in[9];
  const float* dWih  = (const float*)d_in[10];
  const float* dWhh  = (const float*)d_in[11];
  const float* dB    = (const float*)d_in[12];
  const float* Wsrc  = (const float*)d_in[13];
  const float* Wctx  = (const float*)d_in[14];
  const float* Wout  = (const float*)d_in[15];
  const float* bout  = (const float*)d_in[16];

  char* ws = (char*)d_ws;
  size_t off = 0;
  auto al = [&](size_t bytes)->char*{
    char* p = ws + off; off += (bytes + 255) & ~(size_t)255; return p; };

  // --- state region (zeroed every launch with one memset) ---
  char* stateBase = ws;
  unsigned short* hEnc = (unsigned short*)al(262144);  // [2][2][128][256]
  unsigned short* hdec = (unsigned short*)al(262144);  // [2][128][512]
  unsigned short* feed = (unsigned short*)al(131072);  // [128][512]
  unsigned short* ctxb = (unsigned short*)al(131072);  // [128][512]
  unsigned*       cnts = (unsigned*)al(45056);         // 352 counter lines
  const size_t stateBytes = off;

  // --- persistent-per-launch scratch (fully rewritten each launch) ---
  unsigned short* emb    = (unsigned short*)al(16777216);  // (S,B,256) bf16
  unsigned short* win    = (unsigned short*)al(4194304);   // (T,B,64) bf16
  unsigned short* encOut = (unsigned short*)al(33554432);  // (B,S,512) bf16
  unsigned short* proj   = (unsigned short*)al(33554432);  // (B,2,S,256) bf16
  unsigned short* WF     = (unsigned short*)al(1048576);   // 1024x512
  unsigned short* WB     = (unsigned short*)al(1048576);
  unsigned short* WDx    = (unsigned short*)al(4456448);   // swizzled 2048x1088
  unsigned short* WCx    = (unsigned short*)al(1048576);   // swizzled 512x1024
  unsigned short* WSP    = (unsigned short*)al(524288);    // swizzled 512x512 (proj B)
  float*          scp    = (float*)al(262144);             // [128][2][256]
  float* bFr = (float*)al(4096);
  float* bBr = (float*)al(4096);
  float* bDr = (float*)al(8192);
  (void)ws_size; (void)in_sizes; (void)n_in; (void)out_size;

  float* out_main = (float*)d_out;
  float* out_attn = out_main + (size_t)B*T*DOF;

  const dim3 blk(256);
  k_build_encw <<<4096,  blk, 0, stream>>>(eWihF, eWhhF, eWihB, eWhhB, WF, WB);
  k_build_decw <<<8704,  blk, 0, stream>>>(dWih, dWhh, WDx);
  k_build_wcx  <<<2048,  blk, 0, stream>>>(Wctx, WCx);
  k_build_wsp  <<<1024,  blk, 0, stream>>>(Wsrc, WSP);
  k_build_bias <<<16,    blk, 0, stream>>>(ebF, ebB, dB, bFr, bBr, bDr);
  k_embed      <<<32768, blk, 0, stream>>>(in_seq, embedding, emb);
  k_win        <<<8192,  blk, 0, stream>>>(tgt, win);
  hipMemsetAsync(stateBase, 0, stateBytes, stream);

  // persistent encoder: 256 steps internally
  k_encoder<<<256, blk, 0, stream>>>(emb, WF, WB, bFr, bBr, hEnc, encOut,
                                     cnts + (size_t)ENC_OFF*CLINE);

  // one-shot proj GEMM (step-invariant attention projection)
  k_proj<<<4096, blk, 0, stream>>>(encOut, WSP, proj);

  // persistent decoder: 256 steps internally (proj in LDS, enc tile in VGPRs,
  // chunked MFMA phases to stay under the register budget)
  k_decoder<<<256, blk, 0, stream>>>(win, WDx, bDr, WCx, proj, encOut, in_seq,
                                     Wout, bout, hdec, feed, ctxb, scp,
                                     out_main, out_attn, cnts);
}

// Round 7
// 8830.186 us; speedup vs baseline: 1.2226x; 1.0066x over previous
//
#include <hip/hip_runtime.h>
#include <stdint.h>

// Problem constants (match reference)
#define B 128
#define S 256
#define T 256
#define EMBED 256
#define ENC 256
#define DEC 512
#define DOF 4

typedef __attribute__((ext_vector_type(8))) short bf16x8;   // 8 bf16 = 4 VGPRs (MFMA A/B frag)
typedef __attribute__((ext_vector_type(4))) float f32x4;    // MFMA C/D frag

static __device__ __forceinline__ float bf2f(unsigned short u){
  union{uint32_t u;float f;}c; c.u = ((uint32_t)u)<<16; return c.f;
}
static __device__ __forceinline__ unsigned short f2bf(float f){
  union{float f;uint32_t u;}c; c.f=f; uint32_t u=c.u;
  u += 0x7fffu + ((u>>16)&1u);  // round-to-nearest-even
  return (unsigned short)(u>>16);
}
static __device__ __forceinline__ void unp2(uint32_t w, float&a, float&b){
  union{uint32_t u;float f;}c1,c2; c1.u = w<<16; c2.u = w & 0xffff0000u; a=c1.f; b=c2.f;
}
static __device__ __forceinline__ float sigm(float x){ return 1.0f/(1.0f+__expf(-x)); }

// ---------------------------------------------------------------------------
// Coherent (agent-scope, cache-bypassing) accessors for cross-block state.
// Read-only data (weights, proj, encW, win, emb) uses NORMAL cached loads.
// ---------------------------------------------------------------------------
static __device__ __forceinline__ unsigned long long ldc8(const void* p){
  return __hip_atomic_load((unsigned long long*)p, __ATOMIC_RELAXED, __HIP_MEMORY_SCOPE_AGENT);
}
static __device__ __forceinline__ void stc8(void* p, unsigned long long v){
  __hip_atomic_store((unsigned long long*)p, v, __ATOMIC_RELAXED, __HIP_MEMORY_SCOPE_AGENT);
}
static __device__ __forceinline__ void stc4(void* p, unsigned v){
  __hip_atomic_store((unsigned*)p, v, __ATOMIC_RELAXED, __HIP_MEMORY_SCOPE_AGENT);
}
static __device__ __forceinline__ void stc4f(float* p, float v){
  __hip_atomic_store((unsigned*)p, __float_as_uint(v), __ATOMIC_RELAXED, __HIP_MEMORY_SCOPE_AGENT);
}
static __device__ __forceinline__ float ldc4f(const float* p){
  return __uint_as_float(__hip_atomic_load((const unsigned*)p, __ATOMIC_RELAXED, __HIP_MEMORY_SCOPE_AGENT));
}
union F16x8 { unsigned long long q[2]; bf16x8 v; unsigned short s[8]; };
union Ubf   { bf16x8 v; uint32_t u[4]; unsigned short s[8]; };
static __device__ __forceinline__ bf16x8 ldfrag_c(const unsigned short* p){
  F16x8 u; u.q[0] = ldc8(p); u.q[1] = ldc8(p + 4); return u.v;
}
static __device__ __forceinline__ unsigned long long pack4bf(float a,float b,float c,float d){
  return (unsigned long long)f2bf(a) | ((unsigned long long)f2bf(b)<<16)
       | ((unsigned long long)f2bf(c)<<32) | ((unsigned long long)f2bf(d)<<48);
}

// ---------------------------------------------------------------------------
// Spread-counter device barriers.
// A: 64 lines x 4 arrivals/step.  F: 64 lines x 4 arrivals/step (line=bid>>2;
// feed for batches 0..63 comes from bids 0..127 -> lines 0..31, so even gates
// blocks subset-wait mask 31).  PAIR: 1 line/batch.
// ---------------------------------------------------------------------------
#define CLINE 32   // u32 per counter line (128 B)
#define A_OFF 0
#define F_OFF 128
#define PAIR_OFF 192
#define ENC_OFF 320
static __device__ __forceinline__ unsigned* cl(unsigned* c, int line){ return c + (size_t)line*CLINE; }

static __device__ __forceinline__ void bar_arr(unsigned* line){
  __builtin_amdgcn_s_waitcnt(0);     // drain this wave's coherent stores
  __syncthreads();                   // all waves drained
  if (threadIdx.x == 0)
    __hip_atomic_fetch_add(line, 1u, __ATOMIC_RELAXED, __HIP_MEMORY_SCOPE_AGENT);
}
static __device__ __forceinline__ void barw(unsigned* set, unsigned target, int mask){
  if (threadIdx.x < 64){
    unsigned* p = set + (size_t)(threadIdx.x & mask)*CLINE;
    while (!__all((int)(__hip_atomic_load(p, __ATOMIC_RELAXED, __HIP_MEMORY_SCOPE_AGENT) >= target)))
      __builtin_amdgcn_s_sleep(1);
  }
  __syncthreads();
  asm volatile("" ::: "memory");
}

// swizzled LDS index (in shorts) for encS: row s (0..255), 16B-chunk c (0..31)
static __device__ __forceinline__ int enc_idx(int s, int c){
  return s*256 + (((c & 24) | ((c ^ s) & 7)) << 3);
}

// ---------------------------------------------------------------------------
// Persistent bi-LSTM encoder. Grid 256 = dir(2) x mg(2) x ng(64).
// ---------------------------------------------------------------------------
__global__ __launch_bounds__(256,1) void k_encoder(
  const unsigned short* __restrict__ emb,   // (S,B,256)
  const unsigned short* __restrict__ WF, const unsigned short* __restrict__ WB,
  const float* __restrict__ bF, const float* __restrict__ bB,
  unsigned short* __restrict__ hEnc,        // [dir][2][B][256]
  unsigned short* __restrict__ encOut,      // [B][S][512]
  unsigned* __restrict__ cntBase)           // 2 sets of 16 lines
{
  __shared__ __align__(16) unsigned short Ws[16*520];
  __shared__ __align__(16) float Gs[64*17];
  __shared__ float bsh[16];
  const int bid = blockIdx.x;
  const int dir = bid >> 7;
  const int mg  = (bid >> 6) & 1;
  const int ng  = bid & 63;
  const int tid = threadIdx.x;
  const int lane = tid & 63, w = tid >> 6;
  const int l16 = lane & 15, qd = lane >> 4;
  const int m_base = mg * 64;
  unsigned* mycnt = cntBase + (size_t)dir*16*CLINE;
  unsigned* myline = cl(mycnt, bid & 15);

  const unsigned short* Wg = (dir ? WB : WF) + (size_t)ng*16*512;
  for (int i = tid; i < 16*64; i += 256){
    const int r = i >> 6, s = i & 63;
    *(uint4*)&Ws[r*520 + s*8] = *(const uint4*)&Wg[r*512 + s*8];
  }
  if (tid < 16) bsh[tid] = (dir ? bB : bF)[ng*16 + tid];
  float c[4] = {0.f,0.f,0.f,0.f};
  __syncthreads();

  for (int t = 0; t < S; ++t){
    const int tt = dir ? (S-1-t) : t;
    const unsigned short* Ae = emb + ((size_t)tt*B + m_base + w*16 + l16)*256 + qd*8;
    bf16x8 av[8];
#pragma unroll
    for (int ks = 0; ks < 8; ++ks) av[ks] = *(const bf16x8*)(Ae + ks*32);   // prefetch (cached)
    if (t) barw(mycnt, (unsigned)(8u*(unsigned)t), 15);
    const unsigned short* Ah = hEnc + (((size_t)dir*2 + (size_t)(t&1))*B + m_base + w*16 + l16)*256 + qd*8;
    bf16x8 hf[8];
#pragma unroll
    for (int ks = 0; ks < 8; ++ks) hf[ks] = ldfrag_c(Ah + ks*32);
    f32x4 acc = (f32x4){0.f,0.f,0.f,0.f};
#pragma unroll
    for (int ks = 0; ks < 8; ++ks){
      bf16x8 bb = *(const bf16x8*)&Ws[l16*520 + ks*32 + qd*8];
      acc = __builtin_amdgcn_mfma_f32_16x16x32_bf16(av[ks], bb, acc, 0, 0, 0);
    }
#pragma unroll
    for (int ks = 0; ks < 8; ++ks){
      bf16x8 bb = *(const bf16x8*)&Ws[l16*520 + 256 + ks*32 + qd*8];
      acc = __builtin_amdgcn_mfma_f32_16x16x32_bf16(hf[ks], bb, acc, 0, 0, 0);
    }
    __syncthreads();
#pragma unroll
    for (int r = 0; r < 4; ++r)
      Gs[(w*16 + qd*4 + r)*17 + l16] = acc[r];
    __syncthreads();
    if (tid < 64){
      const int bl = tid;
      float hv[4];
#pragma unroll
      for (int u = 0; u < 4; ++u){
        const float gi = Gs[bl*17 + u*4 + 0] + bsh[u*4 + 0];
        const float gf = Gs[bl*17 + u*4 + 1] + bsh[u*4 + 1];
        const float gg = Gs[bl*17 + u*4 + 2] + bsh[u*4 + 2];
        const float go = Gs[bl*17 + u*4 + 3] + bsh[u*4 + 3];
        const float cn = sigm(gf)*c[u] + sigm(gi)*tanhf(gg);
        c[u] = cn;
        hv[u] = sigm(go)*tanhf(cn);
      }
      const int b2 = m_base + bl;
      const unsigned long long hq = pack4bf(hv[0],hv[1],hv[2],hv[3]);
      stc8(&hEnc[(((size_t)dir*2 + (size_t)((t+1)&1))*B + b2)*256 + ng*4], hq);
      *(unsigned long long*)&encOut[((size_t)b2*S + tt)*512 + dir*256 + ng*4] = hq;
    }
    bar_arr(myline);
  }
}

// ---------------------------------------------------------------------------
// One-shot precompute of BOTH step-invariant attention matrices:
//   proj = encOut @ W_src^T  (scores)        -> (B, 2, S, 256) d-half-major
//   encW = encOut @ Wc^T     (ctx-part feed) -> (B, 2, S, 256) n-half-major
// Grid 4096 = mtile(512) x ntile(8); 64 rows per block; A-frags shared.
// ---------------------------------------------------------------------------
__global__ __launch_bounds__(256,2) void k_proj(
  const unsigned short* __restrict__ encOut,  // (B*S, 512)
  const unsigned short* __restrict__ WSP,     // swizzled W_src B-frags (n=d, k=e)
  const unsigned short* __restrict__ WCP,     // swizzled Wc B-frags (n=dec, k=e)
  unsigned short* __restrict__ proj,          // (B, 2, S, 256)
  unsigned short* __restrict__ encW)          // (B, 2, S, 256)
{
  const int nb = blockIdx.x & 7;
  const int mt = blockIdx.x >> 3;
  const int tid = threadIdx.x;
  const int lane = tid & 63, w = tid >> 6;
  const int l16 = lane & 15, qd = lane >> 4;
  const int m0 = mt*64 + w*16;
  const unsigned short* Ap = encOut + ((size_t)m0 + l16)*512 + qd*8;
  bf16x8 av[16];
#pragma unroll
  for (int ks = 0; ks < 16; ++ks) av[ks] = *(const bf16x8*)(Ap + ks*32);
  for (int which = 0; which < 2; ++which){
    const unsigned short* Wb = which ? WCP : WSP;
    unsigned short* outp = which ? encW : proj;
    for (int nn = 0; nn < 4; ++nn){
      const int qn = nb*4 + nn;          // 16-wide n group
      const unsigned short* Bq = Wb + (size_t)qn*16*512 + (size_t)lane*8;
      f32x4 acc = (f32x4){0.f,0.f,0.f,0.f};
#pragma unroll
      for (int ks = 0; ks < 16; ++ks){
        bf16x8 bb = *(const bf16x8*)(Bq + (size_t)ks*512);
        acc = __builtin_amdgcn_mfma_f32_16x16x32_bf16(av[ks], bb, acc, 0, 0, 0);
      }
      const int d = qn*16 + l16, dh = d >> 8, dl = d & 255;
#pragma unroll
      for (int r = 0; r < 4; ++r){
        const int m = m0 + qd*4 + r;
        const int bb2 = m >> 8, s = m & 255;
        outp[(((size_t)bb2*2 + dh)*256 + s)*256 + dl] = f2bf(acc[r]);
      }
    }
  }
}

// ---------------------------------------------------------------------------
// Persistent decoder, 2-hop chain. Grid 256; block i owns (b=i>>1, eh=i&1):
//   LDS: proj[b, :, eh*256..+256) swizzled (128 KB), all steps.
//   VGPR: encW[b, :, eh*256..+256) (ev[32], 128 VGPR), all steps.
// Each block produces feed[b, eh-half] ITSELF:
//   feed[n] = tanh( h.Wctx[n,:512] (GEMV, hidden under pair wait)
//                 + sum_s aw[s]*encW[s,n] (registers) )
// Per step: [pre: h-part gates] -> Fwait(subset) -> w_t+feed gates -> barA
//   -> scores -> pair-arrive -> GEMV -> pair-wait -> softmax -> v -> feed
//   -> barF.   (2 hops + pair)
// ---------------------------------------------------------------------------
__global__ __launch_bounds__(256,1) void k_decoder(
  const unsigned short* __restrict__ win,    // (T,B,64)
  const unsigned short* __restrict__ WDx,    // swizzled gates weights
  const float* __restrict__ bD,              // 2048 reordered
  const unsigned short* __restrict__ WhP,    // packed h-part of W_ctx (GEMV)
  const unsigned short* __restrict__ projq,  // (B,2,S,256)
  const unsigned short* __restrict__ encWq,  // (B,2,S,256)
  const int* __restrict__ in_seq,
  const float* __restrict__ Wout, const float* __restrict__ bout,
  unsigned short* __restrict__ hdec,         // [2][B][512]
  unsigned short* __restrict__ feed,         // [B][512]
  float* __restrict__ scp,                   // [B][2][256] partial scores
  float* __restrict__ out_main, float* __restrict__ out_attn,
  unsigned* __restrict__ cnts)
{
  __shared__ __align__(16) unsigned short encS[65536];  // 128 KB resident proj tile
  __shared__ __align__(16) float scrf[2080];
  __shared__ float bsh[16];
  const int bid = blockIdx.x;
  const int b  = bid >> 1, eh = bid & 1;
  const int mg = bid & 1, ng = (bid >> 1) & 127;
  const int tid = threadIdx.x;
  const int lane = tid & 63, w = tid >> 6;
  const int l16 = lane & 15, qd = lane >> 4;
  const int m_base = mg*64;

  // ---- init: bias, mask, resident proj tile (LDS) ----
  if (tid < 16) bsh[tid] = bD[ng*16 + tid];
  const int mymask = (in_seq[b*S + tid] == 0);
  {
    const unsigned short* Pq = projq + (((size_t)b*2 + eh)*256)*256;
    for (int i = 0; i < 32; ++i){
      const int s = i*8 + (tid>>5), cc = tid & 31;
      const uint4 v = *(const uint4*)&Pq[(size_t)s*256 + cc*8];
      *(uint4*)&encS[enc_idx(s, cc)] = v;
    }
  }
  // ---- init: encW n-half tile in REGISTERS (step-invariant) ----
  bf16x8 ev[32];
  {
    const int cc = lane & 31, par = lane >> 5;
    const unsigned short* Ep = encWq + (((size_t)b*2 + eh)*256)*256 + cc*8;
#pragma unroll
    for (int i2 = 0; i2 < 32; ++i2)
      ev[i2] = *(const bf16x8*)(Ep + (size_t)(w*64 + i2*2 + par)*256);
  }
  float c[4] = {0.f,0.f,0.f,0.f};
  __syncthreads();

  for (int t = 0; t < T; ++t){
    // ---------------- phase A: gates + LSTM update (chunked MFMA) ----------
    const int row = m_base + w*16 + l16;
    const unsigned short* Aw = win  + ((size_t)t*B + row)*64 + qd*8;
    const unsigned short* Af = feed + (size_t)row*512 + qd*8;
    const unsigned short* Ah = hdec + ((size_t)(t&1)*B + row)*512 + qd*8;
    const unsigned short* Bp = WDx + (size_t)ng*34*512 + (size_t)lane*8;
    f32x4 acc = (f32x4){0.f,0.f,0.f,0.f};
    // pre-wait: h-part of gates (h_{t-1} visible since prev barA) — off chain
#pragma unroll
    for (int ch = 0; ch < 2; ++ch){
      bf16x8 hv[8];
#pragma unroll
      for (int i = 0; i < 8; ++i) hv[i] = ldfrag_c(Ah + (ch*8 + i)*32);
#pragma unroll
      for (int ks = 0; ks < 8; ++ks){
        bf16x8 bb = *(const bf16x8*)(Bp + (size_t)(18 + ch*8 + ks)*512);
        acc = __builtin_amdgcn_mfma_f32_16x16x32_bf16(hv[ks], bb, acc, 0, 0, 0);
      }
    }
    bf16x8 a0 = *(const bf16x8*)(Aw);
    bf16x8 a1 = *(const bf16x8*)(Aw + 32);
    // feed_{t-1} ready: even blocks consume rows 0..63 (bids 0..127 -> lines
    // 0..31, mask 31); odd blocks also outproj arbitrary row -> mask 63.
    if (t){
      if (bid & 1) barw(cl(cnts, F_OFF), (unsigned)(4u*(unsigned)t), 63);
      else         barw(cl(cnts, F_OFF), (unsigned)(4u*(unsigned)t), 31);
    }
    {   // w_t part
      bf16x8 b0 = *(const bf16x8*)(Bp);
      bf16x8 b1 = *(const bf16x8*)(Bp + 512);
      acc = __builtin_amdgcn_mfma_f32_16x16x32_bf16(a0, b0, acc, 0, 0, 0);
      acc = __builtin_amdgcn_mfma_f32_16x16x32_bf16(a1, b1, acc, 0, 0, 0);
    }
#pragma unroll
    for (int ch = 0; ch < 2; ++ch){   // feed part, chunks of 8
      bf16x8 av[8], bv[8];
#pragma unroll
      for (int i = 0; i < 8; ++i){
        av[i] = ldfrag_c(Af + (ch*8 + i)*32);
        bv[i] = *(const bf16x8*)(Bp + (size_t)(2 + ch*8 + i)*512);
      }
#pragma unroll
      for (int ks = 0; ks < 8; ++ks)
        acc = __builtin_amdgcn_mfma_f32_16x16x32_bf16(av[ks], bv[ks], acc, 0, 0, 0);
    }
    __syncthreads();
#pragma unroll
    for (int r = 0; r < 4; ++r)
      scrf[(w*16 + qd*4 + r)*17 + l16] = acc[r];
    __syncthreads();
    if (tid < 64){
      float hv[4];
#pragma unroll
      for (int u = 0; u < 4; ++u){
        const float gi = scrf[tid*17 + u*4 + 0] + bsh[u*4 + 0];
        const float gf = scrf[tid*17 + u*4 + 1] + bsh[u*4 + 1];
        const float gg = scrf[tid*17 + u*4 + 2] + bsh[u*4 + 2];
        const float go = scrf[tid*17 + u*4 + 3] + bsh[u*4 + 3];
        const float cn = sigm(gf)*c[u] + sigm(gi)*tanhf(gg);
        c[u] = cn;
        hv[u] = sigm(go)*tanhf(cn);
      }
      stc8(&hdec[((size_t)((t+1)&1)*B + m_base + tid)*512 + ng*4],
           pack4bf(hv[0],hv[1],hv[2],hv[3]));
    }
    bar_arr(cl(cnts, A_OFF + (bid & 63)));

    // out-projection of feed_{t-1} (odd blocks; overlaps barA stragglers)
    if ((bid & 1) && t > 0){
      const int b2o = bid >> 1;
      const int d = tid >> 6, kk = lane;
      const unsigned short* fp = feed + (size_t)b2o*512 + kk*8;
      F16x8 u; u.q[0] = ldc8(fp); u.q[1] = ldc8(fp + 4);
      const float* wp = Wout + d*512 + kk*8;
      float p = 0.f;
#pragma unroll
      for (int j2 = 0; j2 < 8; ++j2) p += bf2f(u.s[j2]) * wp[j2];
#pragma unroll
      for (int off = 32; off > 0; off >>= 1) p += __shfl_down(p, off, 64);
      if (kk == 0){
        const float v = p + bout[d];
        out_main[((size_t)b2o*T + (t-1))*4 + d] = (d < 3) ? tanhf(v) : fmaxf(v, 0.f);
      }
    }

    // ---------------- attention + feed (all blocks; half of batch b) --------
    barw(cl(cnts, A_OFF), (unsigned)(4u*(unsigned)(t+1)), 63);   // full h_t visible
    if (tid < 64){   // full h[b] -> scrf[0..511]
      const unsigned short* hp = hdec + ((size_t)((t+1)&1)*B + b)*512 + tid*8;
      F16x8 uh; uh.q[0] = ldc8(hp); uh.q[1] = ldc8(hp + 4);
#pragma unroll
      for (int j = 0; j < 8; ++j) scrf[tid*8 + j] = bf2f(uh.s[j]);
    }
    __syncthreads();
    // scores for all 256 s (this block's d-half of the dot)
    float sc = 0.f;
#pragma unroll 8
    for (int cix = 0; cix < 32; ++cix){
      Ubf u8; u8.v = *(const bf16x8*)&encS[enc_idx(tid, cix)];
      float f0,f1,f2,f3,f4,f5,f6,f7;
      unp2(u8.u[0],f0,f1); unp2(u8.u[1],f2,f3); unp2(u8.u[2],f4,f5); unp2(u8.u[3],f6,f7);
      const float* qp = &scrf[eh*256 + cix*8];
      sc += f0*qp[0] + f1*qp[1] + f2*qp[2] + f3*qp[3]
          + f4*qp[4] + f5*qp[5] + f6*qp[6] + f7*qp[7];
    }
    stc4f(&scp[((size_t)b*2 + eh)*256 + tid], sc);
    // pair ARRIVE (split so the GEMV below hides the pair latency)
    __builtin_amdgcn_s_waitcnt(0);
    __syncthreads();
    if (tid == 0)
      __hip_atomic_fetch_add(cl(cnts, PAIR_OFF + b), 1u, __ATOMIC_RELAXED, __HIP_MEMORY_SCOPE_AGENT);
    // hW GEMV: n = eh*256+tid, hw = sum_k h[k]*Wctx[n,k]  (L2-hot weights)
    float hw0 = 0.f, hw1 = 0.f, hw2 = 0.f, hw3 = 0.f;
    {
      const unsigned short* Wp = WhP + (size_t)(eh*256 + tid)*8;
#pragma unroll 8
      for (int kc = 0; kc < 64; ++kc){
        Ubf u8; u8.v = *(const bf16x8*)(Wp + (size_t)kc*4096);
        const float4 h0 = *(const float4*)&scrf[kc*8];
        const float4 h1 = *(const float4*)&scrf[kc*8 + 4];
        float f0,f1,f2,f3,f4,f5,f6,f7;
        unp2(u8.u[0],f0,f1); unp2(u8.u[1],f2,f3); unp2(u8.u[2],f4,f5); unp2(u8.u[3],f6,f7);
        hw0 += h0.x*f0 + h1.x*f4;
        hw1 += h0.y*f1 + h1.y*f5;
        hw2 += h0.z*f2 + h1.z*f6;
        hw3 += h0.w*f3 + h1.w*f7;
      }
    }
    const float hw = (hw0 + hw1) + (hw2 + hw3);
    // pair WAIT (peer's partial scores visible after this)
    if (tid == 0){
      unsigned* pp = cl(cnts, PAIR_OFF + b);
      while (__hip_atomic_load(pp, __ATOMIC_RELAXED, __HIP_MEMORY_SCOPE_AGENT) < 2u*(unsigned)(t+1))
        __builtin_amdgcn_s_sleep(1);
    }
    __syncthreads();
    asm volatile("" ::: "memory");
    float tot = sc + ldc4f(&scp[((size_t)b*2 + (1-eh))*256 + tid]);
    if (mymask) tot = -1e30f;
    // softmax over 256 s
    float mx = tot;
#pragma unroll
    for (int off = 32; off > 0; off >>= 1) mx = fmaxf(mx, __shfl_xor(mx, off, 64));
    if (lane == 0) scrf[768 + w] = mx;
    __syncthreads();
    mx = fmaxf(fmaxf(scrf[768], scrf[769]), fmaxf(scrf[770], scrf[771]));
    const float e = __expf(tot - mx);
    float l = e;
#pragma unroll
    for (int off = 32; off > 0; off >>= 1) l += __shfl_xor(l, off, 64);
    if (lane == 0) scrf[772 + w] = l;
    __syncthreads();
    l = scrf[772] + scrf[773] + scrf[774] + scrf[775];
    const float aw = e / l;
    scrf[512 + tid] = aw;
    if (eh == 0) __builtin_nontemporal_store(aw, &out_attn[((size_t)b*T + t)*S + tid]);
    __syncthreads();
    // v[n-half] from REGISTERS (ev): wave w covers 64 s rows (2 per iter)
    {
      float a[8] = {0,0,0,0,0,0,0,0};
      const int cc = lane & 31, par = lane >> 5;
#pragma unroll
      for (int i2 = 0; i2 < 32; ++i2){
        const int srow = w*64 + i2*2 + par;
        const float wgt = scrf[512 + srow];
        Ubf u8; u8.v = ev[i2];
        float f0,f1,f2,f3,f4,f5,f6,f7;
        unp2(u8.u[0],f0,f1); unp2(u8.u[1],f2,f3); unp2(u8.u[2],f4,f5); unp2(u8.u[3],f6,f7);
        a[0]+=wgt*f0; a[1]+=wgt*f1; a[2]+=wgt*f2; a[3]+=wgt*f3;
        a[4]+=wgt*f4; a[5]+=wgt*f5; a[6]+=wgt*f6; a[7]+=wgt*f7;
      }
#pragma unroll
      for (int j2 = 0; j2 < 8; ++j2) a[j2] += __shfl_xor(a[j2], 32, 64);
      if (par == 0){
#pragma unroll
        for (int j2 = 0; j2 < 8; ++j2) scrf[784 + w*256 + cc*8 + j2] = a[j2];
      }
    }
    __syncthreads();
    // feed[b, eh*256 + tid] = tanh(hw + v)
    {
      const float v = scrf[784 + tid] + scrf[784 + 256 + tid]
                    + scrf[784 + 512 + tid] + scrf[784 + 768 + tid];
      scrf[1808 + tid] = tanhf(hw + v);
    }
    __syncthreads();
    if (tid < 128){
      const int n2 = tid*2;
      stc4(&feed[(size_t)b*512 + eh*256 + n2],
           (unsigned)f2bf(scrf[1808 + n2]) | ((unsigned)f2bf(scrf[1808 + n2 + 1]) << 16));
    }
    bar_arr(cl(cnts, F_OFF + (bid >> 2)));   // 4 arrivals/line/step
  }
  // final out-projection (feed_255)
  if (bid & 1){
    barw(cl(cnts, F_OFF), (unsigned)(4u*256u), 63);
    const int b2o = bid >> 1;
    const int d = tid >> 6, kk = lane;
    const unsigned short* fp = feed + (size_t)b2o*512 + kk*8;
    F16x8 u; u.q[0] = ldc8(fp); u.q[1] = ldc8(fp + 4);
    const float* wp = Wout + d*512 + kk*8;
    float p = 0.f;
#pragma unroll
    for (int j2 = 0; j2 < 8; ++j2) p += bf2f(u.s[j2]) * wp[j2];
#pragma unroll
    for (int off = 32; off > 0; off >>= 1) p += __shfl_down(p, off, 64);
    if (kk == 0){
      const float v = p + bout[d];
      out_main[((size_t)b2o*T + 255)*4 + d] = (d < 3) ? tanhf(v) : fmaxf(v, 0.f);
    }
  }
}

// ---------------- setup / builder kernels ----------------
__global__ __launch_bounds__(256) void k_build_encw(
  const float* __restrict__ WihF, const float* __restrict__ WhhF,
  const float* __restrict__ WihB, const float* __restrict__ WhhB,
  unsigned short* WF, unsigned short* WB)
{
  const int idx = blockIdx.x*256 + threadIdx.x;     // 2*1024*512
  const int dir = idx >> 19;
  const int i2 = idx & 524287;
  const int row = i2 >> 9, col = i2 & 511;
  const int j = row >> 2, g = row & 3;
  const int orig = g*256 + j;
  const float* Wih = dir ? WihB : WihF;
  const float* Whh = dir ? WhhB : WhhF;
  const float v = (col < 256) ? Wih[orig*256 + col] : Whh[orig*256 + (col-256)];
  (dir ? WB : WF)[i2] = f2bf(v);
}

// gates weights: reorder rows (j*4+g), pad cols to 1088, swizzle to frag order
__global__ __launch_bounds__(256) void k_build_decw(
  const float* __restrict__ Wih, const float* __restrict__ Whh, unsigned short* WDx)
{
  const int idx = blockIdx.x*256 + threadIdx.x;
  if (idx >= 2048*1088) return;
  const int row = idx / 1088, col = idx - row*1088;
  const int j = row >> 2, g = row & 3;
  const int orig = g*512 + j;
  float v;
  if (col < 16)        v = Wih[orig*528 + col];          // w_t part
  else if (col < 64)   v = 0.f;                          // pad
  else if (col < 576)  v = Wih[orig*528 + (col - 48)];   // feed part
  else                 v = Whh[orig*512 + (col - 576)];  // h part
  const int ng = row >> 4, l16 = row & 15;
  const int ks = col >> 5, qdd = (col >> 3) & 3, jj = col & 7;
  WDx[(((size_t)ng*34 + ks)*64 + qdd*16 + l16)*8 + jj] = f2bf(v);
}

// h-part of W_ctx packed for GEMV: WhP[(k>>3)*512 + n][k&7] = Wctx[n, k]
__global__ __launch_bounds__(256) void k_build_whp(
  const float* __restrict__ Wctx, unsigned short* WhP)
{
  const int idx = blockIdx.x*256 + threadIdx.x;     // 512*512
  const int k = idx >> 9, n = idx & 511;
  WhP[(((size_t)(k >> 3)*512 + n) << 3) + (k & 7)] = f2bf(Wctx[(size_t)n*1024 + k]);
}

// ctx-part of W_ctx in B-frag order for encW GEMM: n = dec-out, k = e
__global__ __launch_bounds__(256) void k_build_wcp(
  const float* __restrict__ Wctx, unsigned short* WCP)
{
  const int idx = blockIdx.x*256 + threadIdx.x;     // 512*512
  const int n = idx >> 9, e = idx & 511;
  const int qn = n >> 4, l16 = n & 15;
  const int ks = e >> 5, qdd = (e >> 3) & 3, jj = e & 7;
  WCP[(((size_t)qn*16 + ks)*64 + qdd*16 + l16)*8 + jj] = f2bf(Wctx[(size_t)n*1024 + 512 + e]);
}

// W_src in B-frag order for proj GEMM: n = d (512), k = e (512)
__global__ __launch_bounds__(256) void k_build_wsp(
  const float* __restrict__ Wsrc, unsigned short* WSP)
{
  const int idx = blockIdx.x*256 + threadIdx.x;     // 512*512
  const int d = idx >> 9, e = idx & 511;
  const int qn = d >> 4, l16 = d & 15;
  const int ks = e >> 5, qdd = (e >> 3) & 3, jj = e & 7;
  WSP[(((size_t)qn*16 + ks)*64 + qdd*16 + l16)*8 + jj] = f2bf(Wsrc[(size_t)d*512 + e]);
}

__global__ __launch_bounds__(256) void k_build_bias(
  const float* __restrict__ ebF, const float* __restrict__ ebB,
  const float* __restrict__ dB, float* bF, float* bB, float* bD)
{
  const int idx = blockIdx.x*256 + threadIdx.x;     // 4096
  if (idx < 1024) bF[idx] = ebF[(idx&3)*256 + (idx>>2)];
  else if (idx < 2048){ const int i = idx-1024; bB[i] = ebB[(i&3)*256 + (i>>2)]; }
  else { const int i = idx-2048; bD[i] = dB[(i&3)*512 + (i>>2)]; }
}

__global__ __launch_bounds__(256) void k_embed(
  const int* __restrict__ in_seq, const float* __restrict__ table, unsigned short* emb)
{
  const int idx = blockIdx.x*256 + threadIdx.x;     // S*B*256, layout (S,B,E)
  const int e = idx & 255, b = (idx >> 8) & 127, s = idx >> 15;
  const int tok = in_seq[b*S + s];
  emb[idx] = f2bf(table[(size_t)tok*256 + e]);
}

__global__ __launch_bounds__(256) void k_win(
  const float* __restrict__ tgt, unsigned short* win)
{
  const int idx = blockIdx.x*256 + threadIdx.x;     // T*B*64, layout (T,B,64)
  const int c = idx & 63, b = (idx >> 6) & 127, t = idx >> 13;
  float v = 0.f;
  if (c < 16){
    const int k = c >> 2, jj = c & 3;
    const int ts = t + k - 4;
    if (ts >= 0) v = tgt[((size_t)b*T + ts)*4 + jj];
  }
  win[idx] = f2bf(v);
}

// ---------------------------------------------------------------------------
extern "C" void kernel_launch(void* const* d_in, const int* in_sizes, int n_in,
                              void* d_out, int out_size, void* d_ws, size_t ws_size,
                              hipStream_t stream)
{
  const int*   in_seq    = (const int*)d_in[0];
  const float* tgt       = (const float*)d_in[1];
  // d_in[2] = lengths (unused by reference)
  const float* embedding = (const float*)d_in[3];
  const float* eWihF = (const float*)d_in[4];
  const float* eWhhF = (const float*)d_in[5];
  const float* ebF   = (const float*)d_in[6];
  const float* eWihB = (const float*)d_in[7];
  const float* eWhhB = (const float*)d_in[8];
  const float* ebB   = (const float*)d_in[9];
  const float* dWih  = (const float*)d_in[10];
  const float* dWhh  = (const float*)d_in[11];
  const float* dB    = (const float*)d_in[12];
  const float* Wsrc  = (const float*)d_in[13];
  const float* Wctx  = (const float*)d_in[14];
  const float* Wout  = (const float*)d_in[15];
  const float* bout  = (const float*)d_in[16];

  char* ws = (char*)d_ws;
  size_t off = 0;
  auto al = [&](size_t bytes)->char*{
    char* p = ws + off; off += (bytes + 255) & ~(size_t)255; return p; };

  // --- state region (zeroed every launch with one memset) ---
  char* stateBase = ws;
  unsigned short* hEnc = (unsigned short*)al(262144);  // [2][2][128][256]
  unsigned short* hdec = (unsigned short*)al(262144);  // [2][128][512]
  unsigned short* feed = (unsigned short*)al(131072);  // [128][512]
  unsigned*       cnts = (unsigned*)al(45056);         // 352 counter lines
  const size_t stateBytes = off;

  // --- persistent-per-launch scratch (fully rewritten each launch) ---
  unsigned short* emb    = (unsigned short*)al(16777216);  // (S,B,256) bf16
  unsigned short* win    = (unsigned short*)al(4194304);   // (T,B,64) bf16
  unsigned short* encOut = (unsigned short*)al(33554432);  // (B,S,512) bf16
  unsigned short* proj   = (unsigned short*)al(33554432);  // (B,2,S,256) bf16
  unsigned short* encWq  = (unsigned short*)al(33554432);  // (B,2,S,256) bf16
  unsigned short* WF     = (unsigned short*)al(1048576);   // 1024x512
  unsigned short* WB     = (unsigned short*)al(1048576);
  unsigned short* WDx    = (unsigned short*)al(4456448);   // swizzled 2048x1088
  unsigned short* WhP    = (unsigned short*)al(524288);    // packed 512x512 (GEMV)
  unsigned short* WCP    = (unsigned short*)al(524288);    // swizzled 512x512 (encW B)
  unsigned short* WSP    = (unsigned short*)al(524288);    // swizzled 512x512 (proj B)
  float*          scp    = (float*)al(262144);             // [128][2][256]
  float* bFr = (float*)al(4096);
  float* bBr = (float*)al(4096);
  float* bDr = (float*)al(8192);
  (void)ws_size; (void)in_sizes; (void)n_in; (void)out_size;

  float* out_main = (float*)d_out;
  float* out_attn = out_main + (size_t)B*T*DOF;

  const dim3 blk(256);
  k_build_encw <<<4096,  blk, 0, stream>>>(eWihF, eWhhF, eWihB, eWhhB, WF, WB);
  k_build_decw <<<8704,  blk, 0, stream>>>(dWih, dWhh, WDx);
  k_build_whp  <<<1024,  blk, 0, stream>>>(Wctx, WhP);
  k_build_wcp  <<<1024,  blk, 0, stream>>>(Wctx, WCP);
  k_build_wsp  <<<1024,  blk, 0, stream>>>(Wsrc, WSP);
  k_build_bias <<<16,    blk, 0, stream>>>(ebF, ebB, dB, bFr, bBr, bDr);
  k_embed      <<<32768, blk, 0, stream>>>(in_seq, embedding, emb);
  k_win        <<<8192,  blk, 0, stream>>>(tgt, win);
  hipMemsetAsync(stateBase, 0, stateBytes, stream);

  // persistent encoder: 256 steps internally
  k_encoder<<<256, blk, 0, stream>>>(emb, WF, WB, bFr, bBr, hEnc, encOut,
                                     cnts + (size_t)ENC_OFF*CLINE);

  // one-shot proj + encW GEMMs (step-invariant attention matrices)
  k_proj<<<4096, blk, 0, stream>>>(encOut, WSP, WCP, proj, encWq);

  // persistent decoder: 256 steps, 2-hop chain (proj in LDS, encW in VGPRs)
  k_decoder<<<256, blk, 0, stream>>>(win, WDx, bDr, WhP, proj, encWq, in_seq,
                                     Wout, bout, hdec, feed, scp,
                                     out_main, out_attn, cnts);
}

// Round 8
// 8788.978 us; speedup vs baseline: 1.2283x; 1.0047x over previous
//
#include <hip/hip_runtime.h>
#include <stdint.h>

// Problem constants (match reference)
#define B 128
#define S 256
#define T 256
#define EMBED 256
#define ENC 256
#define DEC 512
#define DOF 4

typedef __attribute__((ext_vector_type(8))) short bf16x8;   // 8 bf16 = 4 VGPRs (MFMA A/B frag)
typedef __attribute__((ext_vector_type(4))) float f32x4;    // MFMA C/D frag

static __device__ __forceinline__ float bf2f(unsigned short u){
  union{uint32_t u;float f;}c; c.u = ((uint32_t)u)<<16; return c.f;
}
static __device__ __forceinline__ unsigned short f2bf(float f){
  union{float f;uint32_t u;}c; c.f=f; uint32_t u=c.u;
  u += 0x7fffu + ((u>>16)&1u);  // round-to-nearest-even
  return (unsigned short)(u>>16);
}
static __device__ __forceinline__ void unp2(uint32_t w, float&a, float&b){
  union{uint32_t u;float f;}c1,c2; c1.u = w<<16; c2.u = w & 0xffff0000u; a=c1.f; b=c2.f;
}
static __device__ __forceinline__ float sigm(float x){ return 1.0f/(1.0f+__expf(-x)); }

// ---------------------------------------------------------------------------
// Coherent (agent-scope, cache-bypassing) accessors for cross-block state.
// Read-only data (weights, proj, encW, win, emb) uses NORMAL cached loads.
// ---------------------------------------------------------------------------
static __device__ __forceinline__ unsigned long long ldc8(const void* p){
  return __hip_atomic_load((unsigned long long*)p, __ATOMIC_RELAXED, __HIP_MEMORY_SCOPE_AGENT);
}
static __device__ __forceinline__ void stc8(void* p, unsigned long long v){
  __hip_atomic_store((unsigned long long*)p, v, __ATOMIC_RELAXED, __HIP_MEMORY_SCOPE_AGENT);
}
static __device__ __forceinline__ void stc4(void* p, unsigned v){
  __hip_atomic_store((unsigned*)p, v, __ATOMIC_RELAXED, __HIP_MEMORY_SCOPE_AGENT);
}
static __device__ __forceinline__ void stc4f(float* p, float v){
  __hip_atomic_store((unsigned*)p, __float_as_uint(v), __ATOMIC_RELAXED, __HIP_MEMORY_SCOPE_AGENT);
}
static __device__ __forceinline__ float ldc4f(const float* p){
  return __uint_as_float(__hip_atomic_load((const unsigned*)p, __ATOMIC_RELAXED, __HIP_MEMORY_SCOPE_AGENT));
}
union F16x8 { unsigned long long q[2]; bf16x8 v; unsigned short s[8]; };
union Ubf   { bf16x8 v; uint32_t u[4]; unsigned short s[8]; };
static __device__ __forceinline__ bf16x8 ldfrag_c(const unsigned short* p){
  F16x8 u; u.q[0] = ldc8(p); u.q[1] = ldc8(p + 4); return u.v;
}
static __device__ __forceinline__ unsigned long long pack4bf(float a,float b,float c,float d){
  return (unsigned long long)f2bf(a) | ((unsigned long long)f2bf(b)<<16)
       | ((unsigned long long)f2bf(c)<<32) | ((unsigned long long)f2bf(d)<<48);
}

// ---------------------------------------------------------------------------
// Spread-counter device barriers with BACKOFF polling.
// Poll storm congests the coherence fabric (R7 diagnosis): 256 blocks x 64
// lanes x ~64cyc poll period ~ 256 fabric transactions/cycle. Backoff:
// first poll immediate, then s_sleep(8) (~512 cyc) between polls; only the
// mask+1 lanes that map to distinct lines issue loads.
// A: 64 lines x 4 arrivals/step.  F: 64 lines x 4 arrivals/step.
// PAIR: 1 line/batch.
// ---------------------------------------------------------------------------
#define CLINE 32   // u32 per counter line (128 B)
#define A_OFF 0
#define F_OFF 128
#define PAIR_OFF 192
#define ENC_OFF 320
static __device__ __forceinline__ unsigned* cl(unsigned* c, int line){ return c + (size_t)line*CLINE; }

static __device__ __forceinline__ void bar_arr(unsigned* line){
  __builtin_amdgcn_s_waitcnt(0);     // drain this wave's coherent stores
  __syncthreads();                   // all waves drained
  if (threadIdx.x == 0)
    __hip_atomic_fetch_add(line, 1u, __ATOMIC_RELAXED, __HIP_MEMORY_SCOPE_AGENT);
}
static __device__ __forceinline__ void barw(unsigned* set, unsigned target, int mask){
  if (threadIdx.x < 64){
    unsigned* p = set + (size_t)(threadIdx.x & mask)*CLINE;
    const int mine = (int)threadIdx.x <= mask;   // 1 poll lane per line
    for (;;){
      int ok = 1;
      if (mine)
        ok = (int)(__hip_atomic_load(p, __ATOMIC_RELAXED, __HIP_MEMORY_SCOPE_AGENT) >= target);
      if (__all(ok)) break;
      __builtin_amdgcn_s_sleep(8);   // ~512 cyc backoff: 8x less poll traffic
    }
  }
  __syncthreads();
  asm volatile("" ::: "memory");
}

// swizzled LDS index (in shorts) for encS: row s (0..255), 16B-chunk c (0..31)
static __device__ __forceinline__ int enc_idx(int s, int c){
  return s*256 + (((c & 24) | ((c ^ s) & 7)) << 3);
}

// ---------------------------------------------------------------------------
// Persistent bi-LSTM encoder. Grid 256 = dir(2) x mg(2) x ng(64).
// ---------------------------------------------------------------------------
__global__ __launch_bounds__(256,1) void k_encoder(
  const unsigned short* __restrict__ emb,   // (S,B,256)
  const unsigned short* __restrict__ WF, const unsigned short* __restrict__ WB,
  const float* __restrict__ bF, const float* __restrict__ bB,
  unsigned short* __restrict__ hEnc,        // [dir][2][B][256]
  unsigned short* __restrict__ encOut,      // [B][S][512]
  unsigned* __restrict__ cntBase)           // 2 sets of 16 lines
{
  __shared__ __align__(16) unsigned short Ws[16*520];
  __shared__ __align__(16) float Gs[64*17];
  __shared__ float bsh[16];
  const int bid = blockIdx.x;
  const int dir = bid >> 7;
  const int mg  = (bid >> 6) & 1;
  const int ng  = bid & 63;
  const int tid = threadIdx.x;
  const int lane = tid & 63, w = tid >> 6;
  const int l16 = lane & 15, qd = lane >> 4;
  const int m_base = mg * 64;
  unsigned* mycnt = cntBase + (size_t)dir*16*CLINE;
  unsigned* myline = cl(mycnt, bid & 15);

  const unsigned short* Wg = (dir ? WB : WF) + (size_t)ng*16*512;
  for (int i = tid; i < 16*64; i += 256){
    const int r = i >> 6, s = i & 63;
    *(uint4*)&Ws[r*520 + s*8] = *(const uint4*)&Wg[r*512 + s*8];
  }
  if (tid < 16) bsh[tid] = (dir ? bB : bF)[ng*16 + tid];
  float c[4] = {0.f,0.f,0.f,0.f};
  __syncthreads();

  for (int t = 0; t < S; ++t){
    const int tt = dir ? (S-1-t) : t;
    const unsigned short* Ae = emb + ((size_t)tt*B + m_base + w*16 + l16)*256 + qd*8;
    bf16x8 av[8];
#pragma unroll
    for (int ks = 0; ks < 8; ++ks) av[ks] = *(const bf16x8*)(Ae + ks*32);   // prefetch (cached)
    if (t) barw(mycnt, (unsigned)(8u*(unsigned)t), 15);
    const unsigned short* Ah = hEnc + (((size_t)dir*2 + (size_t)(t&1))*B + m_base + w*16 + l16)*256 + qd*8;
    bf16x8 hf[8];
#pragma unroll
    for (int ks = 0; ks < 8; ++ks) hf[ks] = ldfrag_c(Ah + ks*32);
    f32x4 acc = (f32x4){0.f,0.f,0.f,0.f};
#pragma unroll
    for (int ks = 0; ks < 8; ++ks){
      bf16x8 bb = *(const bf16x8*)&Ws[l16*520 + ks*32 + qd*8];
      acc = __builtin_amdgcn_mfma_f32_16x16x32_bf16(av[ks], bb, acc, 0, 0, 0);
    }
#pragma unroll
    for (int ks = 0; ks < 8; ++ks){
      bf16x8 bb = *(const bf16x8*)&Ws[l16*520 + 256 + ks*32 + qd*8];
      acc = __builtin_amdgcn_mfma_f32_16x16x32_bf16(hf[ks], bb, acc, 0, 0, 0);
    }
    __syncthreads();
#pragma unroll
    for (int r = 0; r < 4; ++r)
      Gs[(w*16 + qd*4 + r)*17 + l16] = acc[r];
    __syncthreads();
    if (tid < 64){
      const int bl = tid;
      float hv[4];
#pragma unroll
      for (int u = 0; u < 4; ++u){
        const float gi = Gs[bl*17 + u*4 + 0] + bsh[u*4 + 0];
        const float gf = Gs[bl*17 + u*4 + 1] + bsh[u*4 + 1];
        const float gg = Gs[bl*17 + u*4 + 2] + bsh[u*4 + 2];
        const float go = Gs[bl*17 + u*4 + 3] + bsh[u*4 + 3];
        const float cn = sigm(gf)*c[u] + sigm(gi)*tanhf(gg);
        c[u] = cn;
        hv[u] = sigm(go)*tanhf(cn);
      }
      const int b2 = m_base + bl;
      const unsigned long long hq = pack4bf(hv[0],hv[1],hv[2],hv[3]);
      stc8(&hEnc[(((size_t)dir*2 + (size_t)((t+1)&1))*B + b2)*256 + ng*4], hq);
      *(unsigned long long*)&encOut[((size_t)b2*S + tt)*512 + dir*256 + ng*4] = hq;
    }
    bar_arr(myline);
  }
}

// ---------------------------------------------------------------------------
// One-shot precompute of BOTH step-invariant attention matrices:
//   proj = encOut @ W_src^T  (scores)        -> (B, 2, S, 256) d-half-major
//   encW = encOut @ Wc^T     (ctx-part feed) -> (B, 2, S, 256) n-half-major
// ---------------------------------------------------------------------------
__global__ __launch_bounds__(256,2) void k_proj(
  const unsigned short* __restrict__ encOut,  // (B*S, 512)
  const unsigned short* __restrict__ WSP,     // swizzled W_src B-frags (n=d, k=e)
  const unsigned short* __restrict__ WCP,     // swizzled Wc B-frags (n=dec, k=e)
  unsigned short* __restrict__ proj,          // (B, 2, S, 256)
  unsigned short* __restrict__ encW)          // (B, 2, S, 256)
{
  const int nb = blockIdx.x & 7;
  const int mt = blockIdx.x >> 3;
  const int tid = threadIdx.x;
  const int lane = tid & 63, w = tid >> 6;
  const int l16 = lane & 15, qd = lane >> 4;
  const int m0 = mt*64 + w*16;
  const unsigned short* Ap = encOut + ((size_t)m0 + l16)*512 + qd*8;
  bf16x8 av[16];
#pragma unroll
  for (int ks = 0; ks < 16; ++ks) av[ks] = *(const bf16x8*)(Ap + ks*32);
  for (int which = 0; which < 2; ++which){
    const unsigned short* Wb = which ? WCP : WSP;
    unsigned short* outp = which ? encW : proj;
    for (int nn = 0; nn < 4; ++nn){
      const int qn = nb*4 + nn;          // 16-wide n group
      const unsigned short* Bq = Wb + (size_t)qn*16*512 + (size_t)lane*8;
      f32x4 acc = (f32x4){0.f,0.f,0.f,0.f};
#pragma unroll
      for (int ks = 0; ks < 16; ++ks){
        bf16x8 bb = *(const bf16x8*)(Bq + (size_t)ks*512);
        acc = __builtin_amdgcn_mfma_f32_16x16x32_bf16(av[ks], bb, acc, 0, 0, 0);
      }
      const int d = qn*16 + l16, dh = d >> 8, dl = d & 255;
#pragma unroll
      for (int r = 0; r < 4; ++r){
        const int m = m0 + qd*4 + r;
        const int bb2 = m >> 8, s = m & 255;
        outp[(((size_t)bb2*2 + dh)*256 + s)*256 + dl] = f2bf(acc[r]);
      }
    }
  }
}

// ---------------------------------------------------------------------------
// Persistent decoder, 2-hop chain. Grid 256; block i owns (b=i>>1, eh=i&1):
//   LDS: proj[b, :, eh*256..+256) swizzled (128 KB), all steps.
//   VGPR: encW[b, :, eh*256..+256) (ev[32], 128 VGPR), all steps.
// Each block produces feed[b, eh-half] ITSELF:
//   feed[n] = tanh( h.Wctx[n,:512] (GEMV, hidden under pair wait)
//                 + sum_s aw[s]*encW[s,n] (registers) )
// Per step: [pre: h-part gates] -> Fwait(subset) -> w_t+feed gates -> barA
//   -> scores -> pair-arrive -> GEMV -> pair-wait -> softmax -> v -> feed
//   -> barF.   (2 hops + pair)
// ---------------------------------------------------------------------------
__global__ __launch_bounds__(256,1) void k_decoder(
  const unsigned short* __restrict__ win,    // (T,B,64)
  const unsigned short* __restrict__ WDx,    // swizzled gates weights
  const float* __restrict__ bD,              // 2048 reordered
  const unsigned short* __restrict__ WhP,    // packed h-part of W_ctx (GEMV)
  const unsigned short* __restrict__ projq,  // (B,2,S,256)
  const unsigned short* __restrict__ encWq,  // (B,2,S,256)
  const int* __restrict__ in_seq,
  const float* __restrict__ Wout, const float* __restrict__ bout,
  unsigned short* __restrict__ hdec,         // [2][B][512]
  unsigned short* __restrict__ feed,         // [B][512]
  float* __restrict__ scp,                   // [B][2][256] partial scores
  float* __restrict__ out_main, float* __restrict__ out_attn,
  unsigned* __restrict__ cnts)
{
  __shared__ __align__(16) unsigned short encS[65536];  // 128 KB resident proj tile
  __shared__ __align__(16) float scrf[2080];
  __shared__ float bsh[16];
  const int bid = blockIdx.x;
  const int b  = bid >> 1, eh = bid & 1;
  const int mg = bid & 1, ng = (bid >> 1) & 127;
  const int tid = threadIdx.x;
  const int lane = tid & 63, w = tid >> 6;
  const int l16 = lane & 15, qd = lane >> 4;
  const int m_base = mg*64;

  // ---- init: bias, mask, resident proj tile (LDS) ----
  if (tid < 16) bsh[tid] = bD[ng*16 + tid];
  const int mymask = (in_seq[b*S + tid] == 0);
  {
    const unsigned short* Pq = projq + (((size_t)b*2 + eh)*256)*256;
    for (int i = 0; i < 32; ++i){
      const int s = i*8 + (tid>>5), cc = tid & 31;
      const uint4 v = *(const uint4*)&Pq[(size_t)s*256 + cc*8];
      *(uint4*)&encS[enc_idx(s, cc)] = v;
    }
  }
  // ---- init: encW n-half tile in REGISTERS (step-invariant) ----
  bf16x8 ev[32];
  {
    const int cc = lane & 31, par = lane >> 5;
    const unsigned short* Ep = encWq + (((size_t)b*2 + eh)*256)*256 + cc*8;
#pragma unroll
    for (int i2 = 0; i2 < 32; ++i2)
      ev[i2] = *(const bf16x8*)(Ep + (size_t)(w*64 + i2*2 + par)*256);
  }
  float c[4] = {0.f,0.f,0.f,0.f};
  __syncthreads();

  for (int t = 0; t < T; ++t){
    // ---------------- phase A: gates + LSTM update (chunked MFMA) ----------
    const int row = m_base + w*16 + l16;
    const unsigned short* Aw = win  + ((size_t)t*B + row)*64 + qd*8;
    const unsigned short* Af = feed + (size_t)row*512 + qd*8;
    const unsigned short* Ah = hdec + ((size_t)(t&1)*B + row)*512 + qd*8;
    const unsigned short* Bp = WDx + (size_t)ng*34*512 + (size_t)lane*8;
    f32x4 acc = (f32x4){0.f,0.f,0.f,0.f};
    // pre-wait: h-part of gates (h_{t-1} visible since prev barA) — off chain
#pragma unroll
    for (int ch = 0; ch < 2; ++ch){
      bf16x8 hv[8];
#pragma unroll
      for (int i = 0; i < 8; ++i) hv[i] = ldfrag_c(Ah + (ch*8 + i)*32);
#pragma unroll
      for (int ks = 0; ks < 8; ++ks){
        bf16x8 bb = *(const bf16x8*)(Bp + (size_t)(18 + ch*8 + ks)*512);
        acc = __builtin_amdgcn_mfma_f32_16x16x32_bf16(hv[ks], bb, acc, 0, 0, 0);
      }
    }
    bf16x8 a0 = *(const bf16x8*)(Aw);
    bf16x8 a1 = *(const bf16x8*)(Aw + 32);
    // feed_{t-1} ready: even blocks consume rows 0..63 (bids 0..127 -> lines
    // 0..31, mask 31); odd blocks also outproj arbitrary row -> mask 63.
    if (t){
      if (bid & 1) barw(cl(cnts, F_OFF), (unsigned)(4u*(unsigned)t), 63);
      else         barw(cl(cnts, F_OFF), (unsigned)(4u*(unsigned)t), 31);
    }
    {   // w_t part
      bf16x8 b0 = *(const bf16x8*)(Bp);
      bf16x8 b1 = *(const bf16x8*)(Bp + 512);
      acc = __builtin_amdgcn_mfma_f32_16x16x32_bf16(a0, b0, acc, 0, 0, 0);
      acc = __builtin_amdgcn_mfma_f32_16x16x32_bf16(a1, b1, acc, 0, 0, 0);
    }
#pragma unroll
    for (int ch = 0; ch < 2; ++ch){   // feed part, chunks of 8
      bf16x8 av[8], bv[8];
#pragma unroll
      for (int i = 0; i < 8; ++i){
        av[i] = ldfrag_c(Af + (ch*8 + i)*32);
        bv[i] = *(const bf16x8*)(Bp + (size_t)(2 + ch*8 + i)*512);
      }
#pragma unroll
      for (int ks = 0; ks < 8; ++ks)
        acc = __builtin_amdgcn_mfma_f32_16x16x32_bf16(av[ks], bv[ks], acc, 0, 0, 0);
    }
    __syncthreads();
#pragma unroll
    for (int r = 0; r < 4; ++r)
      scrf[(w*16 + qd*4 + r)*17 + l16] = acc[r];
    __syncthreads();
    if (tid < 64){
      float hv[4];
#pragma unroll
      for (int u = 0; u < 4; ++u){
        const float gi = scrf[tid*17 + u*4 + 0] + bsh[u*4 + 0];
        const float gf = scrf[tid*17 + u*4 + 1] + bsh[u*4 + 1];
        const float gg = scrf[tid*17 + u*4 + 2] + bsh[u*4 + 2];
        const float go = scrf[tid*17 + u*4 + 3] + bsh[u*4 + 3];
        const float cn = sigm(gf)*c[u] + sigm(gi)*tanhf(gg);
        c[u] = cn;
        hv[u] = sigm(go)*tanhf(cn);
      }
      stc8(&hdec[((size_t)((t+1)&1)*B + m_base + tid)*512 + ng*4],
           pack4bf(hv[0],hv[1],hv[2],hv[3]));
    }
    bar_arr(cl(cnts, A_OFF + (bid & 63)));

    // out-projection of feed_{t-1} (odd blocks; overlaps barA stragglers)
    if ((bid & 1) && t > 0){
      const int b2o = bid >> 1;
      const int d = tid >> 6, kk = lane;
      const unsigned short* fp = feed + (size_t)b2o*512 + kk*8;
      F16x8 u; u.q[0] = ldc8(fp); u.q[1] = ldc8(fp + 4);
      const float* wp = Wout + d*512 + kk*8;
      float p = 0.f;
#pragma unroll
      for (int j2 = 0; j2 < 8; ++j2) p += bf2f(u.s[j2]) * wp[j2];
#pragma unroll
      for (int off = 32; off > 0; off >>= 1) p += __shfl_down(p, off, 64);
      if (kk == 0){
        const float v = p + bout[d];
        out_main[((size_t)b2o*T + (t-1))*4 + d] = (d < 3) ? tanhf(v) : fmaxf(v, 0.f);
      }
    }

    // ---------------- attention + feed (all blocks; half of batch b) --------
    barw(cl(cnts, A_OFF), (unsigned)(4u*(unsigned)(t+1)), 63);   // full h_t visible
    if (tid < 64){   // full h[b] -> scrf[0..511]
      const unsigned short* hp = hdec + ((size_t)((t+1)&1)*B + b)*512 + tid*8;
      F16x8 uh; uh.q[0] = ldc8(hp); uh.q[1] = ldc8(hp + 4);
#pragma unroll
      for (int j = 0; j < 8; ++j) scrf[tid*8 + j] = bf2f(uh.s[j]);
    }
    __syncthreads();
    // scores for all 256 s (this block's d-half of the dot)
    float sc = 0.f;
#pragma unroll 8
    for (int cix = 0; cix < 32; ++cix){
      Ubf u8; u8.v = *(const bf16x8*)&encS[enc_idx(tid, cix)];
      float f0,f1,f2,f3,f4,f5,f6,f7;
      unp2(u8.u[0],f0,f1); unp2(u8.u[1],f2,f3); unp2(u8.u[2],f4,f5); unp2(u8.u[3],f6,f7);
      const float* qp = &scrf[eh*256 + cix*8];
      sc += f0*qp[0] + f1*qp[1] + f2*qp[2] + f3*qp[3]
          + f4*qp[4] + f5*qp[5] + f6*qp[6] + f7*qp[7];
    }
    stc4f(&scp[((size_t)b*2 + eh)*256 + tid], sc);
    // pair ARRIVE (split so the GEMV below hides the pair latency)
    __builtin_amdgcn_s_waitcnt(0);
    __syncthreads();
    if (tid == 0)
      __hip_atomic_fetch_add(cl(cnts, PAIR_OFF + b), 1u, __ATOMIC_RELAXED, __HIP_MEMORY_SCOPE_AGENT);
    // hW GEMV: n = eh*256+tid, hw = sum_k h[k]*Wctx[n,k]  (L2-hot weights)
    float hw0 = 0.f, hw1 = 0.f, hw2 = 0.f, hw3 = 0.f;
    {
      const unsigned short* Wp = WhP + (size_t)(eh*256 + tid)*8;
#pragma unroll 8
      for (int kc = 0; kc < 64; ++kc){
        Ubf u8; u8.v = *(const bf16x8*)(Wp + (size_t)kc*4096);
        const float4 h0 = *(const float4*)&scrf[kc*8];
        const float4 h1 = *(const float4*)&scrf[kc*8 + 4];
        float f0,f1,f2,f3,f4,f5,f6,f7;
        unp2(u8.u[0],f0,f1); unp2(u8.u[1],f2,f3); unp2(u8.u[2],f4,f5); unp2(u8.u[3],f6,f7);
        hw0 += h0.x*f0 + h1.x*f4;
        hw1 += h0.y*f1 + h1.y*f5;
        hw2 += h0.z*f2 + h1.z*f6;
        hw3 += h0.w*f3 + h1.w*f7;
      }
    }
    const float hw = (hw0 + hw1) + (hw2 + hw3);
    // pair WAIT with backoff (peer's partial scores visible after this)
    if (tid == 0){
      unsigned* pp = cl(cnts, PAIR_OFF + b);
      while (__hip_atomic_load(pp, __ATOMIC_RELAXED, __HIP_MEMORY_SCOPE_AGENT) < 2u*(unsigned)(t+1))
        __builtin_amdgcn_s_sleep(4);
    }
    __syncthreads();
    asm volatile("" ::: "memory");
    float tot = sc + ldc4f(&scp[((size_t)b*2 + (1-eh))*256 + tid]);
    if (mymask) tot = -1e30f;
    // softmax over 256 s
    float mx = tot;
#pragma unroll
    for (int off = 32; off > 0; off >>= 1) mx = fmaxf(mx, __shfl_xor(mx, off, 64));
    if (lane == 0) scrf[768 + w] = mx;
    __syncthreads();
    mx = fmaxf(fmaxf(scrf[768], scrf[769]), fmaxf(scrf[770], scrf[771]));
    const float e = __expf(tot - mx);
    float l = e;
#pragma unroll
    for (int off = 32; off > 0; off >>= 1) l += __shfl_xor(l, off, 64);
    if (lane == 0) scrf[772 + w] = l;
    __syncthreads();
    l = scrf[772] + scrf[773] + scrf[774] + scrf[775];
    const float aw = e / l;
    scrf[512 + tid] = aw;
    if (eh == 0) __builtin_nontemporal_store(aw, &out_attn[((size_t)b*T + t)*S + tid]);
    __syncthreads();
    // v[n-half] from REGISTERS (ev): wave w covers 64 s rows (2 per iter)
    {
      float a[8] = {0,0,0,0,0,0,0,0};
      const int cc = lane & 31, par = lane >> 5;
#pragma unroll
      for (int i2 = 0; i2 < 32; ++i2){
        const int srow = w*64 + i2*2 + par;
        const float wgt = scrf[512 + srow];
        Ubf u8; u8.v = ev[i2];
        float f0,f1,f2,f3,f4,f5,f6,f7;
        unp2(u8.u[0],f0,f1); unp2(u8.u[1],f2,f3); unp2(u8.u[2],f4,f5); unp2(u8.u[3],f6,f7);
        a[0]+=wgt*f0; a[1]+=wgt*f1; a[2]+=wgt*f2; a[3]+=wgt*f3;
        a[4]+=wgt*f4; a[5]+=wgt*f5; a[6]+=wgt*f6; a[7]+=wgt*f7;
      }
#pragma unroll
      for (int j2 = 0; j2 < 8; ++j2) a[j2] += __shfl_xor(a[j2], 32, 64);
      if (par == 0){
#pragma unroll
        for (int j2 = 0; j2 < 8; ++j2) scrf[784 + w*256 + cc*8 + j2] = a[j2];
      }
    }
    __syncthreads();
    // feed[b, eh*256 + tid] = tanh(hw + v)
    {
      const float v = scrf[784 + tid] + scrf[784 + 256 + tid]
                    + scrf[784 + 512 + tid] + scrf[784 + 768 + tid];
      scrf[1808 + tid] = tanhf(hw + v);
    }
    __syncthreads();
    if (tid < 128){
      const int n2 = tid*2;
      stc4(&feed[(size_t)b*512 + eh*256 + n2],
           (unsigned)f2bf(scrf[1808 + n2]) | ((unsigned)f2bf(scrf[1808 + n2 + 1]) << 16));
    }
    bar_arr(cl(cnts, F_OFF + (bid >> 2)));   // 4 arrivals/line/step
  }
  // final out-projection (feed_255)
  if (bid & 1){
    barw(cl(cnts, F_OFF), (unsigned)(4u*256u), 63);
    const int b2o = bid >> 1;
    const int d = tid >> 6, kk = lane;
    const unsigned short* fp = feed + (size_t)b2o*512 + kk*8;
    F16x8 u; u.q[0] = ldc8(fp); u.q[1] = ldc8(fp + 4);
    const float* wp = Wout + d*512 + kk*8;
    float p = 0.f;
#pragma unroll
    for (int j2 = 0; j2 < 8; ++j2) p += bf2f(u.s[j2]) * wp[j2];
#pragma unroll
    for (int off = 32; off > 0; off >>= 1) p += __shfl_down(p, off, 64);
    if (kk == 0){
      const float v = p + bout[d];
      out_main[((size_t)b2o*T + 255)*4 + d] = (d < 3) ? tanhf(v) : fmaxf(v, 0.f);
    }
  }
}

// ---------------- setup / builder kernels ----------------
__global__ __launch_bounds__(256) void k_build_encw(
  const float* __restrict__ WihF, const float* __restrict__ WhhF,
  const float* __restrict__ WihB, const float* __restrict__ WhhB,
  unsigned short* WF, unsigned short* WB)
{
  const int idx = blockIdx.x*256 + threadIdx.x;     // 2*1024*512
  const int dir = idx >> 19;
  const int i2 = idx & 524287;
  const int row = i2 >> 9, col = i2 & 511;
  const int j = row >> 2, g = row & 3;
  const int orig = g*256 + j;
  const float* Wih = dir ? WihB : WihF;
  const float* Whh = dir ? WhhB : WhhF;
  const float v = (col < 256) ? Wih[orig*256 + col] : Whh[orig*256 + (col-256)];
  (dir ? WB : WF)[i2] = f2bf(v);
}

// gates weights: reorder rows (j*4+g), pad cols to 1088, swizzle to frag order
__global__ __launch_bounds__(256) void k_build_decw(
  const float* __restrict__ Wih, const float* __restrict__ Whh, unsigned short* WDx)
{
  const int idx = blockIdx.x*256 + threadIdx.x;
  if (idx >= 2048*1088) return;
  const int row = idx / 1088, col = idx - row*1088;
  const int j = row >> 2, g = row & 3;
  const int orig = g*512 + j;
  float v;
  if (col < 16)        v = Wih[orig*528 + col];          // w_t part
  else if (col < 64)   v = 0.f;                          // pad
  else if (col < 576)  v = Wih[orig*528 + (col - 48)];   // feed part
  else                 v = Whh[orig*512 + (col - 576)];  // h part
  const int ng = row >> 4, l16 = row & 15;
  const int ks = col >> 5, qdd = (col >> 3) & 3, jj = col & 7;
  WDx[(((size_t)ng*34 + ks)*64 + qdd*16 + l16)*8 + jj] = f2bf(v);
}

// h-part of W_ctx packed for GEMV: WhP[(k>>3)*512 + n][k&7] = Wctx[n, k]
__global__ __launch_bounds__(256) void k_build_whp(
  const float* __restrict__ Wctx, unsigned short* WhP)
{
  const int idx = blockIdx.x*256 + threadIdx.x;     // 512*512
  const int k = idx >> 9, n = idx & 511;
  WhP[(((size_t)(k >> 3)*512 + n) << 3) + (k & 7)] = f2bf(Wctx[(size_t)n*1024 + k]);
}

// ctx-part of W_ctx in B-frag order for encW GEMM: n = dec-out, k = e
__global__ __launch_bounds__(256) void k_build_wcp(
  const float* __restrict__ Wctx, unsigned short* WCP)
{
  const int idx = blockIdx.x*256 + threadIdx.x;     // 512*512
  const int n = idx >> 9, e = idx & 511;
  const int qn = n >> 4, l16 = n & 15;
  const int ks = e >> 5, qdd = (e >> 3) & 3, jj = e & 7;
  WCP[(((size_t)qn*16 + ks)*64 + qdd*16 + l16)*8 + jj] = f2bf(Wctx[(size_t)n*1024 + 512 + e]);
}

// W_src in B-frag order for proj GEMM: n = d (512), k = e (512)
__global__ __launch_bounds__(256) void k_build_wsp(
  const float* __restrict__ Wsrc, unsigned short* WSP)
{
  const int idx = blockIdx.x*256 + threadIdx.x;     // 512*512
  const int d = idx >> 9, e = idx & 511;
  const int qn = d >> 4, l16 = d & 15;
  const int ks = e >> 5, qdd = (e >> 3) & 3, jj = e & 7;
  WSP[(((size_t)qn*16 + ks)*64 + qdd*16 + l16)*8 + jj] = f2bf(Wsrc[(size_t)d*512 + e]);
}

__global__ __launch_bounds__(256) void k_build_bias(
  const float* __restrict__ ebF, const float* __restrict__ ebB,
  const float* __restrict__ dB, float* bF, float* bB, float* bD)
{
  const int idx = blockIdx.x*256 + threadIdx.x;     // 4096
  if (idx < 1024) bF[idx] = ebF[(idx&3)*256 + (idx>>2)];
  else if (idx < 2048){ const int i = idx-1024; bB[i] = ebB[(i&3)*256 + (i>>2)]; }
  else { const int i = idx-2048; bD[i] = dB[(i&3)*512 + (i>>2)]; }
}

__global__ __launch_bounds__(256) void k_embed(
  const int* __restrict__ in_seq, const float* __restrict__ table, unsigned short* emb)
{
  const int idx = blockIdx.x*256 + threadIdx.x;     // S*B*256, layout (S,B,E)
  const int e = idx & 255, b = (idx >> 8) & 127, s = idx >> 15;
  const int tok = in_seq[b*S + s];
  emb[idx] = f2bf(table[(size_t)tok*256 + e]);
}

__global__ __launch_bounds__(256) void k_win(
  const float* __restrict__ tgt, unsigned short* win)
{
  const int idx = blockIdx.x*256 + threadIdx.x;     // T*B*64, layout (T,B,64)
  const int c = idx & 63, b = (idx >> 6) & 127, t = idx >> 13;
  float v = 0.f;
  if (c < 16){
    const int k = c >> 2, jj = c & 3;
    const int ts = t + k - 4;
    if (ts >= 0) v = tgt[((size_t)b*T + ts)*4 + jj];
  }
  win[idx] = f2bf(v);
}

// ---------------------------------------------------------------------------
extern "C" void kernel_launch(void* const* d_in, const int* in_sizes, int n_in,
                              void* d_out, int out_size, void* d_ws, size_t ws_size,
                              hipStream_t stream)
{
  const int*   in_seq    = (const int*)d_in[0];
  const float* tgt       = (const float*)d_in[1];
  // d_in[2] = lengths (unused by reference)
  const float* embedding = (const float*)d_in[3];
  const float* eWihF = (const float*)d_in[4];
  const float* eWhhF = (const float*)d_in[5];
  const float* ebF   = (const float*)d_in[6];
  const float* eWihB = (const float*)d_in[7];
  const float* eWhhB = (const float*)d_in[8];
  const float* ebB   = (const float*)d_in[9];
  const float* dWih  = (const float*)d_in[10];
  const float* dWhh  = (const float*)d_in[11];
  const float* dB    = (const float*)d_in[12];
  const float* Wsrc  = (const float*)d_in[13];
  const float* Wctx  = (const float*)d_in[14];
  const float* Wout  = (const float*)d_in[15];
  const float* bout  = (const float*)d_in[16];

  char* ws = (char*)d_ws;
  size_t off = 0;
  auto al = [&](size_t bytes)->char*{
    char* p = ws + off; off += (bytes + 255) & ~(size_t)255; return p; };

  // --- state region (zeroed every launch with one memset) ---
  char* stateBase = ws;
  unsigned short* hEnc = (unsigned short*)al(262144);  // [2][2][128][256]
  unsigned short* hdec = (unsigned short*)al(262144);  // [2][128][512]
  unsigned short* feed = (unsigned short*)al(131072);  // [128][512]
  unsigned*       cnts = (unsigned*)al(45056);         // 352 counter lines
  const size_t stateBytes = off;

  // --- persistent-per-launch scratch (fully rewritten each launch) ---
  unsigned short* emb    = (unsigned short*)al(16777216);  // (S,B,256) bf16
  unsigned short* win    = (unsigned short*)al(4194304);   // (T,B,64) bf16
  unsigned short* encOut = (unsigned short*)al(33554432);  // (B,S,512) bf16
  unsigned short* proj   = (unsigned short*)al(33554432);  // (B,2,S,256) bf16
  unsigned short* encWq  = (unsigned short*)al(33554432);  // (B,2,S,256) bf16
  unsigned short* WF     = (unsigned short*)al(1048576);   // 1024x512
  unsigned short* WB     = (unsigned short*)al(1048576);
  unsigned short* WDx    = (unsigned short*)al(4456448);   // swizzled 2048x1088
  unsigned short* WhP    = (unsigned short*)al(524288);    // packed 512x512 (GEMV)
  unsigned short* WCP    = (unsigned short*)al(524288);    // swizzled 512x512 (encW B)
  unsigned short* WSP    = (unsigned short*)al(524288);    // swizzled 512x512 (proj B)
  float*          scp    = (float*)al(262144);             // [128][2][256]
  float* bFr = (float*)al(4096);
  float* bBr = (float*)al(4096);
  float* bDr = (float*)al(8192);
  (void)ws_size; (void)in_sizes; (void)n_in; (void)out_size;

  float* out_main = (float*)d_out;
  float* out_attn = out_main + (size_t)B*T*DOF;

  const dim3 blk(256);
  k_build_encw <<<4096,  blk, 0, stream>>>(eWihF, eWhhF, eWihB, eWhhB, WF, WB);
  k_build_decw <<<8704,  blk, 0, stream>>>(dWih, dWhh, WDx);
  k_build_whp  <<<1024,  blk, 0, stream>>>(Wctx, WhP);
  k_build_wcp  <<<1024,  blk, 0, stream>>>(Wctx, WCP);
  k_build_wsp  <<<1024,  blk, 0, stream>>>(Wsrc, WSP);
  k_build_bias <<<16,    blk, 0, stream>>>(ebF, ebB, dB, bFr, bBr, bDr);
  k_embed      <<<32768, blk, 0, stream>>>(in_seq, embedding, emb);
  k_win        <<<8192,  blk, 0, stream>>>(tgt, win);
  hipMemsetAsync(stateBase, 0, stateBytes, stream);

  // persistent encoder: 256 steps internally
  k_encoder<<<256, blk, 0, stream>>>(emb, WF, WB, bFr, bBr, hEnc, encOut,
                                     cnts + (size_t)ENC_OFF*CLINE);

  // one-shot proj + encW GEMMs (step-invariant attention matrices)
  k_proj<<<4096, blk, 0, stream>>>(encOut, WSP, WCP, proj, encWq);

  // persistent decoder: 256 steps, 2-hop chain (proj in LDS, encW in VGPRs,
  // backoff polling on all cross-block waits)
  k_decoder<<<256, blk, 0, stream>>>(win, WDx, bDr, WhP, proj, encWq, in_seq,
                                     Wout, bout, hdec, feed, scp,
                                     out_main, out_attn, cnts);
}

// Round 9
// 8593.914 us; speedup vs baseline: 1.2562x; 1.0227x over previous
//
#include <hip/hip_runtime.h>
#include <stdint.h>

// Problem constants (match reference)
#define B 128
#define S 256
#define T 256
#define EMBED 256
#define ENC 256
#define DEC 512
#define DOF 4

typedef __attribute__((ext_vector_type(8))) short bf16x8;   // 8 bf16 = 4 VGPRs (MFMA A/B frag)
typedef __attribute__((ext_vector_type(4))) float f32x4;    // MFMA C/D frag

static __device__ __forceinline__ float bf2f(unsigned short u){
  union{uint32_t u;float f;}c; c.u = ((uint32_t)u)<<16; return c.f;
}
static __device__ __forceinline__ unsigned short f2bf(float f){
  union{float f;uint32_t u;}c; c.f=f; uint32_t u=c.u;
  u += 0x7fffu + ((u>>16)&1u);  // round-to-nearest-even
  return (unsigned short)(u>>16);
}
static __device__ __forceinline__ void unp2(uint32_t w, float&a, float&b){
  union{uint32_t u;float f;}c1,c2; c1.u = w<<16; c2.u = w & 0xffff0000u; a=c1.f; b=c2.f;
}
static __device__ __forceinline__ float sigm(float x){ return 1.0f/(1.0f+__expf(-x)); }

// ---------------------------------------------------------------------------
// Coherent (agent-scope, cache-bypassing) accessors for cross-block state.
// Read-only data (weights, proj, encW, win, emb) uses NORMAL cached loads.
// ---------------------------------------------------------------------------
static __device__ __forceinline__ unsigned long long ldc8(const void* p){
  return __hip_atomic_load((unsigned long long*)p, __ATOMIC_RELAXED, __HIP_MEMORY_SCOPE_AGENT);
}
static __device__ __forceinline__ void stc8(void* p, unsigned long long v){
  __hip_atomic_store((unsigned long long*)p, v, __ATOMIC_RELAXED, __HIP_MEMORY_SCOPE_AGENT);
}
static __device__ __forceinline__ void stc4(void* p, unsigned v){
  __hip_atomic_store((unsigned*)p, v, __ATOMIC_RELAXED, __HIP_MEMORY_SCOPE_AGENT);
}
static __device__ __forceinline__ void stc4f(float* p, float v){
  __hip_atomic_store((unsigned*)p, __float_as_uint(v), __ATOMIC_RELAXED, __HIP_MEMORY_SCOPE_AGENT);
}
static __device__ __forceinline__ float ldc4f(const float* p){
  return __uint_as_float(__hip_atomic_load((const unsigned*)p, __ATOMIC_RELAXED, __HIP_MEMORY_SCOPE_AGENT));
}
union F16x8 { unsigned long long q[2]; bf16x8 v; unsigned short s[8]; };
union Ubf   { bf16x8 v; uint32_t u[4]; unsigned short s[8]; };
static __device__ __forceinline__ bf16x8 ldfrag_c(const unsigned short* p){
  F16x8 u; u.q[0] = ldc8(p); u.q[1] = ldc8(p + 4); return u.v;
}
static __device__ __forceinline__ unsigned long long pack4bf(float a,float b,float c,float d){
  return (unsigned long long)f2bf(a) | ((unsigned long long)f2bf(b)<<16)
       | ((unsigned long long)f2bf(c)<<32) | ((unsigned long long)f2bf(d)<<48);
}

// ---------------------------------------------------------------------------
// GROUP-SCOPE barriers (R9): 8 independent groups x 32 blocks x 16 batches.
// No inter-group synchronization at all — straggler max is over 32 blocks,
// and group-level jitter averages across steps instead of compounding.
// A: 256 lines (1/block, 1 arrival/step).  F: 256 lines (1/block).
// PAIR: 128 lines (1/batch).  ENC: 32 lines.
// ---------------------------------------------------------------------------
#define CLINE 32   // u32 per counter line (128 B)
#define A_OFF 0
#define F_OFF 256
#define PAIR_OFF 512
#define ENC_OFF 640
static __device__ __forceinline__ unsigned* cl(unsigned* c, int line){ return c + (size_t)line*CLINE; }

static __device__ __forceinline__ void bar_arr(unsigned* line){
  __builtin_amdgcn_s_waitcnt(0);     // drain this wave's coherent stores
  __syncthreads();                   // all waves drained
  if (threadIdx.x == 0)
    __hip_atomic_fetch_add(line, 1u, __ATOMIC_RELAXED, __HIP_MEMORY_SCOPE_AGENT);
}
static __device__ __forceinline__ void barw(unsigned* set, unsigned target, int mask){
  if (threadIdx.x < 64){
    unsigned* p = set + (size_t)(threadIdx.x & mask)*CLINE;
    const int mine = (int)threadIdx.x <= mask;   // 1 poll lane per line
    for (;;){
      int ok = 1;
      if (mine)
        ok = (int)(__hip_atomic_load(p, __ATOMIC_RELAXED, __HIP_MEMORY_SCOPE_AGENT) >= target);
      if (__all(ok)) break;
      __builtin_amdgcn_s_sleep(8);
    }
  }
  __syncthreads();
  asm volatile("" ::: "memory");
}

// swizzled LDS index (in shorts) for encS: row s (0..255), 16B-chunk c (0..31)
static __device__ __forceinline__ int enc_idx(int s, int c){
  return s*256 + (((c & 24) | ((c ^ s) & 7)) << 3);
}

// ---------------------------------------------------------------------------
// Persistent bi-LSTM encoder. Grid 256 = dir(2) x mg(2) x ng(64).
// ---------------------------------------------------------------------------
__global__ __launch_bounds__(256,1) void k_encoder(
  const unsigned short* __restrict__ emb,   // (S,B,256)
  const unsigned short* __restrict__ WF, const unsigned short* __restrict__ WB,
  const float* __restrict__ bF, const float* __restrict__ bB,
  unsigned short* __restrict__ hEnc,        // [dir][2][B][256]
  unsigned short* __restrict__ encOut,      // [B][S][512]
  unsigned* __restrict__ cntBase)           // 2 sets of 16 lines
{
  __shared__ __align__(16) unsigned short Ws[16*520];
  __shared__ __align__(16) float Gs[64*17];
  __shared__ float bsh[16];
  const int bid = blockIdx.x;
  const int dir = bid >> 7;
  const int mg  = (bid >> 6) & 1;
  const int ng  = bid & 63;
  const int tid = threadIdx.x;
  const int lane = tid & 63, w = tid >> 6;
  const int l16 = lane & 15, qd = lane >> 4;
  const int m_base = mg * 64;
  unsigned* mycnt = cntBase + (size_t)dir*16*CLINE;
  unsigned* myline = cl(mycnt, bid & 15);

  const unsigned short* Wg = (dir ? WB : WF) + (size_t)ng*16*512;
  for (int i = tid; i < 16*64; i += 256){
    const int r = i >> 6, s = i & 63;
    *(uint4*)&Ws[r*520 + s*8] = *(const uint4*)&Wg[r*512 + s*8];
  }
  if (tid < 16) bsh[tid] = (dir ? bB : bF)[ng*16 + tid];
  float c[4] = {0.f,0.f,0.f,0.f};
  __syncthreads();

  for (int t = 0; t < S; ++t){
    const int tt = dir ? (S-1-t) : t;
    const unsigned short* Ae = emb + ((size_t)tt*B + m_base + w*16 + l16)*256 + qd*8;
    bf16x8 av[8];
#pragma unroll
    for (int ks = 0; ks < 8; ++ks) av[ks] = *(const bf16x8*)(Ae + ks*32);   // prefetch (cached)
    if (t) barw(mycnt, (unsigned)(8u*(unsigned)t), 15);
    const unsigned short* Ah = hEnc + (((size_t)dir*2 + (size_t)(t&1))*B + m_base + w*16 + l16)*256 + qd*8;
    bf16x8 hf[8];
#pragma unroll
    for (int ks = 0; ks < 8; ++ks) hf[ks] = ldfrag_c(Ah + ks*32);
    f32x4 acc = (f32x4){0.f,0.f,0.f,0.f};
#pragma unroll
    for (int ks = 0; ks < 8; ++ks){
      bf16x8 bb = *(const bf16x8*)&Ws[l16*520 + ks*32 + qd*8];
      acc = __builtin_amdgcn_mfma_f32_16x16x32_bf16(av[ks], bb, acc, 0, 0, 0);
    }
#pragma unroll
    for (int ks = 0; ks < 8; ++ks){
      bf16x8 bb = *(const bf16x8*)&Ws[l16*520 + 256 + ks*32 + qd*8];
      acc = __builtin_amdgcn_mfma_f32_16x16x32_bf16(hf[ks], bb, acc, 0, 0, 0);
    }
    __syncthreads();
#pragma unroll
    for (int r = 0; r < 4; ++r)
      Gs[(w*16 + qd*4 + r)*17 + l16] = acc[r];
    __syncthreads();
    if (tid < 64){
      const int bl = tid;
      float hv[4];
#pragma unroll
      for (int u = 0; u < 4; ++u){
        const float gi = Gs[bl*17 + u*4 + 0] + bsh[u*4 + 0];
        const float gf = Gs[bl*17 + u*4 + 1] + bsh[u*4 + 1];
        const float gg = Gs[bl*17 + u*4 + 2] + bsh[u*4 + 2];
        const float go = Gs[bl*17 + u*4 + 3] + bsh[u*4 + 3];
        const float cn = sigm(gf)*c[u] + sigm(gi)*tanhf(gg);
        c[u] = cn;
        hv[u] = sigm(go)*tanhf(cn);
      }
      const int b2 = m_base + bl;
      const unsigned long long hq = pack4bf(hv[0],hv[1],hv[2],hv[3]);
      stc8(&hEnc[(((size_t)dir*2 + (size_t)((t+1)&1))*B + b2)*256 + ng*4], hq);
      *(unsigned long long*)&encOut[((size_t)b2*S + tt)*512 + dir*256 + ng*4] = hq;
    }
    bar_arr(myline);
  }
}

// ---------------------------------------------------------------------------
// One-shot precompute of BOTH step-invariant attention matrices:
//   proj = encOut @ W_src^T  (scores)        -> (B, 2, S, 256) d-half-major
//   encW = encOut @ Wc^T     (ctx-part feed) -> (B, 2, S, 256) n-half-major
// ---------------------------------------------------------------------------
__global__ __launch_bounds__(256,2) void k_proj(
  const unsigned short* __restrict__ encOut,  // (B*S, 512)
  const unsigned short* __restrict__ WSP,     // swizzled W_src B-frags (n=d, k=e)
  const unsigned short* __restrict__ WCP,     // swizzled Wc B-frags (n=dec, k=e)
  unsigned short* __restrict__ proj,          // (B, 2, S, 256)
  unsigned short* __restrict__ encW)          // (B, 2, S, 256)
{
  const int nb = blockIdx.x & 7;
  const int mt = blockIdx.x >> 3;
  const int tid = threadIdx.x;
  const int lane = tid & 63, w = tid >> 6;
  const int l16 = lane & 15, qd = lane >> 4;
  const int m0 = mt*64 + w*16;
  const unsigned short* Ap = encOut + ((size_t)m0 + l16)*512 + qd*8;
  bf16x8 av[16];
#pragma unroll
  for (int ks = 0; ks < 16; ++ks) av[ks] = *(const bf16x8*)(Ap + ks*32);
  for (int which = 0; which < 2; ++which){
    const unsigned short* Wb = which ? WCP : WSP;
    unsigned short* outp = which ? encW : proj;
    for (int nn = 0; nn < 4; ++nn){
      const int qn = nb*4 + nn;          // 16-wide n group
      const unsigned short* Bq = Wb + (size_t)qn*16*512 + (size_t)lane*8;
      f32x4 acc = (f32x4){0.f,0.f,0.f,0.f};
#pragma unroll
      for (int ks = 0; ks < 16; ++ks){
        bf16x8 bb = *(const bf16x8*)(Bq + (size_t)ks*512);
        acc = __builtin_amdgcn_mfma_f32_16x16x32_bf16(av[ks], bb, acc, 0, 0, 0);
      }
      const int d = qn*16 + l16, dh = d >> 8, dl = d & 255;
#pragma unroll
      for (int r = 0; r < 4; ++r){
        const int m = m0 + qd*4 + r;
        const int bb2 = m >> 8, s = m & 255;
        outp[(((size_t)bb2*2 + dh)*256 + s)*256 + dl] = f2bf(acc[r]);
      }
    }
  }
}

// ---------------------------------------------------------------------------
// Persistent decoder, GROUP-LOCAL sync (R9). Grid 256 = 8 groups x 32 blocks.
// Group g owns batches g*16..g*16+15; ZERO cross-group synchronization.
// Block j of group g:
//   gates: 16 batches x 64 gate-cols (wave w -> col-group j*4+w); M=16 MFMA.
//   LSTM:  1 c value/thread (16 batches x 16 dims).
//   attn:  b = g*16 + (j>>1), eh = j&1 (proj half in LDS, encW half in VGPRs)
//   feed[n] = tanh(h.Wctx[n,:512] (GEMV under pair) + sum_s aw*encW[s,n])
// Per step: Fwait(grp) -> gates -> barA-arr; outproj; barA-wait(grp)
//   -> scores -> pair-arrive -> GEMV -> pair-wait -> softmax -> v -> feed
//   -> barF-arr.
// ---------------------------------------------------------------------------
__global__ __launch_bounds__(256,1) void k_decoder(
  const unsigned short* __restrict__ win,    // (T,B,64)
  const unsigned short* __restrict__ WDx,    // swizzled gates weights
  const float* __restrict__ bD,              // 2048 reordered
  const unsigned short* __restrict__ WhP,    // packed h-part of W_ctx (GEMV)
  const unsigned short* __restrict__ projq,  // (B,2,S,256)
  const unsigned short* __restrict__ encWq,  // (B,2,S,256)
  const int* __restrict__ in_seq,
  const float* __restrict__ Wout, const float* __restrict__ bout,
  unsigned short* __restrict__ hdec,         // [2][B][512]
  unsigned short* __restrict__ feed,         // [B][512]
  float* __restrict__ scp,                   // [B][2][256] partial scores
  float* __restrict__ out_main, float* __restrict__ out_attn,
  unsigned* __restrict__ cnts)
{
  __shared__ __align__(16) unsigned short encS[65536];  // 128 KB resident proj tile
  __shared__ __align__(16) float scrf[2080];
  __shared__ float bsh[64];
  const int bid = blockIdx.x;
  const int j = bid & 31, g = bid >> 5;
  const int gb0 = g*16;
  const int b  = gb0 + (j >> 1), eh = j & 1;
  const int tid = threadIdx.x;
  const int lane = tid & 63, w = tid >> 6;
  const int l16 = lane & 15, qd = lane >> 4;
  unsigned* Aset = cl(cnts, A_OFF + g*32);
  unsigned* Fset = cl(cnts, F_OFF + g*32);

  // ---- init: bias (block's 64 gate cols), mask, resident proj tile ----
  if (tid < 64) bsh[tid] = bD[j*64 + tid];
  const int mymask = (in_seq[b*S + tid] == 0);
  {
    const unsigned short* Pq = projq + (((size_t)b*2 + eh)*256)*256;
    for (int i = 0; i < 32; ++i){
      const int s = i*8 + (tid>>5), cc = tid & 31;
      const uint4 v = *(const uint4*)&Pq[(size_t)s*256 + cc*8];
      *(uint4*)&encS[enc_idx(s, cc)] = v;
    }
  }
  // ---- init: encW n-half tile in REGISTERS (step-invariant) ----
  bf16x8 ev[32];
  {
    const int cc = lane & 31, par = lane >> 5;
    const unsigned short* Ep = encWq + (((size_t)b*2 + eh)*256)*256 + cc*8;
#pragma unroll
    for (int i2 = 0; i2 < 32; ++i2)
      ev[i2] = *(const bf16x8*)(Ep + (size_t)(w*64 + i2*2 + par)*256);
  }
  float cst = 0.f;   // LSTM cell state: 1 value/thread (batch tid>>4, dim tid&15)
  __syncthreads();

  for (int t = 0; t < T; ++t){
    // ---------------- phase A: gates (M=16) + LSTM update ----------------
    const unsigned short* Aw = win  + ((size_t)t*B + gb0 + l16)*64 + qd*8;
    const unsigned short* Af = feed + (size_t)(gb0 + l16)*512 + qd*8;
    const unsigned short* Ah = hdec + ((size_t)(t&1)*B + gb0 + l16)*512 + qd*8;
    const unsigned short* Bp = WDx + (size_t)(j*4 + w)*34*512 + (size_t)lane*8;
    f32x4 acc = (f32x4){0.f,0.f,0.f,0.f};
    // pre-wait: h-part of gates (h_{t-1} visible since prev barA) — off chain
#pragma unroll
    for (int ch = 0; ch < 2; ++ch){
      bf16x8 hv[8];
#pragma unroll
      for (int i = 0; i < 8; ++i) hv[i] = ldfrag_c(Ah + (ch*8 + i)*32);
#pragma unroll
      for (int ks = 0; ks < 8; ++ks){
        bf16x8 bb = *(const bf16x8*)(Bp + (size_t)(18 + ch*8 + ks)*512);
        acc = __builtin_amdgcn_mfma_f32_16x16x32_bf16(hv[ks], bb, acc, 0, 0, 0);
      }
    }
    bf16x8 a0 = *(const bf16x8*)(Aw);
    bf16x8 a1 = *(const bf16x8*)(Aw + 32);
    // feed_{t-1} ready (group-scope: all 32 group blocks arrived t times)
    if (t) barw(Fset, (unsigned)t, 31);
    {   // w_t part
      bf16x8 b0 = *(const bf16x8*)(Bp);
      bf16x8 b1 = *(const bf16x8*)(Bp + 512);
      acc = __builtin_amdgcn_mfma_f32_16x16x32_bf16(a0, b0, acc, 0, 0, 0);
      acc = __builtin_amdgcn_mfma_f32_16x16x32_bf16(a1, b1, acc, 0, 0, 0);
    }
#pragma unroll
    for (int ch = 0; ch < 2; ++ch){   // feed part, chunks of 8
      bf16x8 av[8], bv[8];
#pragma unroll
      for (int i = 0; i < 8; ++i){
        av[i] = ldfrag_c(Af + (ch*8 + i)*32);
        bv[i] = *(const bf16x8*)(Bp + (size_t)(2 + ch*8 + i)*512);
      }
#pragma unroll
      for (int ks = 0; ks < 8; ++ks)
        acc = __builtin_amdgcn_mfma_f32_16x16x32_bf16(av[ks], bv[ks], acc, 0, 0, 0);
    }
    __syncthreads();
    // C: row (qd*4+r) = batch 0..15, col l16 = gate col of wave's 16
#pragma unroll
    for (int r = 0; r < 4; ++r)
      scrf[(qd*4 + r)*68 + w*17 + l16] = acc[r];
    __syncthreads();
    {
      const int bl = tid >> 4, di = tid & 15;   // batch-in-group, dim-in-block
      const int ws = di >> 2, u = di & 3;
      const float gi = scrf[bl*68 + ws*17 + u*4 + 0] + bsh[ws*16 + u*4 + 0];
      const float gf = scrf[bl*68 + ws*17 + u*4 + 1] + bsh[ws*16 + u*4 + 1];
      const float gg = scrf[bl*68 + ws*17 + u*4 + 2] + bsh[ws*16 + u*4 + 2];
      const float go = scrf[bl*68 + ws*17 + u*4 + 3] + bsh[ws*16 + u*4 + 3];
      const float cn = sigm(gf)*cst + sigm(gi)*tanhf(gg);
      cst = cn;
      const float hv = sigm(go)*tanhf(cn);
      const float v1 = __shfl_down(hv, 1, 64);
      const float v2 = __shfl_down(hv, 2, 64);
      const float v3 = __shfl_down(hv, 3, 64);
      if ((di & 3) == 0)
        stc8(&hdec[((size_t)((t+1)&1)*B + gb0 + bl)*512 + j*16 + di],
             pack4bf(hv, v1, v2, v3));
    }
    bar_arr(cl(cnts, A_OFF + bid));

    // out-projection of feed_{t-1} (odd j; own batch b; overlaps barA stragglers)
    if ((j & 1) && t > 0){
      const int d = tid >> 6, kk = lane;
      const unsigned short* fp = feed + (size_t)b*512 + kk*8;
      F16x8 u; u.q[0] = ldc8(fp); u.q[1] = ldc8(fp + 4);
      const float* wp = Wout + d*512 + kk*8;
      float p = 0.f;
#pragma unroll
      for (int j2 = 0; j2 < 8; ++j2) p += bf2f(u.s[j2]) * wp[j2];
#pragma unroll
      for (int off = 32; off > 0; off >>= 1) p += __shfl_down(p, off, 64);
      if (kk == 0){
        const float v = p + bout[d];
        out_main[((size_t)b*T + (t-1))*4 + d] = (d < 3) ? tanhf(v) : fmaxf(v, 0.f);
      }
    }

    // ---------------- attention + feed (half of batch b) --------------------
    barw(Aset, (unsigned)(t+1), 31);   // full h_t of group visible
    if (tid < 64){   // full h[b] -> scrf[0..511]
      const unsigned short* hp = hdec + ((size_t)((t+1)&1)*B + b)*512 + tid*8;
      F16x8 uh; uh.q[0] = ldc8(hp); uh.q[1] = ldc8(hp + 4);
#pragma unroll
      for (int jj = 0; jj < 8; ++jj) scrf[tid*8 + jj] = bf2f(uh.s[jj]);
    }
    __syncthreads();
    // scores for all 256 s (this block's d-half of the dot)
    float sc = 0.f;
#pragma unroll 8
    for (int cix = 0; cix < 32; ++cix){
      Ubf u8; u8.v = *(const bf16x8*)&encS[enc_idx(tid, cix)];
      float f0,f1,f2,f3,f4,f5,f6,f7;
      unp2(u8.u[0],f0,f1); unp2(u8.u[1],f2,f3); unp2(u8.u[2],f4,f5); unp2(u8.u[3],f6,f7);
      const float* qp = &scrf[eh*256 + cix*8];
      sc += f0*qp[0] + f1*qp[1] + f2*qp[2] + f3*qp[3]
          + f4*qp[4] + f5*qp[5] + f6*qp[6] + f7*qp[7];
    }
    stc4f(&scp[((size_t)b*2 + eh)*256 + tid], sc);
    // pair ARRIVE (split so the GEMV below hides the pair latency)
    __builtin_amdgcn_s_waitcnt(0);
    __syncthreads();
    if (tid == 0)
      __hip_atomic_fetch_add(cl(cnts, PAIR_OFF + b), 1u, __ATOMIC_RELAXED, __HIP_MEMORY_SCOPE_AGENT);
    // hW GEMV: n = eh*256+tid, hw = sum_k h[k]*Wctx[n,k]  (L2-hot weights)
    float hw0 = 0.f, hw1 = 0.f, hw2 = 0.f, hw3 = 0.f;
    {
      const unsigned short* Wp = WhP + (size_t)(eh*256 + tid)*8;
#pragma unroll 8
      for (int kc = 0; kc < 64; ++kc){
        Ubf u8; u8.v = *(const bf16x8*)(Wp + (size_t)kc*4096);
        const float4 h0 = *(const float4*)&scrf[kc*8];
        const float4 h1 = *(const float4*)&scrf[kc*8 + 4];
        float f0,f1,f2,f3,f4,f5,f6,f7;
        unp2(u8.u[0],f0,f1); unp2(u8.u[1],f2,f3); unp2(u8.u[2],f4,f5); unp2(u8.u[3],f6,f7);
        hw0 += h0.x*f0 + h1.x*f4;
        hw1 += h0.y*f1 + h1.y*f5;
        hw2 += h0.z*f2 + h1.z*f6;
        hw3 += h0.w*f3 + h1.w*f7;
      }
    }
    const float hw = (hw0 + hw1) + (hw2 + hw3);
    // pair WAIT with backoff (peer's partial scores visible after this)
    if (tid == 0){
      unsigned* pp = cl(cnts, PAIR_OFF + b);
      while (__hip_atomic_load(pp, __ATOMIC_RELAXED, __HIP_MEMORY_SCOPE_AGENT) < 2u*(unsigned)(t+1))
        __builtin_amdgcn_s_sleep(4);
    }
    __syncthreads();
    asm volatile("" ::: "memory");
    float tot = sc + ldc4f(&scp[((size_t)b*2 + (1-eh))*256 + tid]);
    if (mymask) tot = -1e30f;
    // softmax over 256 s
    float mx = tot;
#pragma unroll
    for (int off = 32; off > 0; off >>= 1) mx = fmaxf(mx, __shfl_xor(mx, off, 64));
    if (lane == 0) scrf[768 + w] = mx;
    __syncthreads();
    mx = fmaxf(fmaxf(scrf[768], scrf[769]), fmaxf(scrf[770], scrf[771]));
    const float e = __expf(tot - mx);
    float l = e;
#pragma unroll
    for (int off = 32; off > 0; off >>= 1) l += __shfl_xor(l, off, 64);
    if (lane == 0) scrf[772 + w] = l;
    __syncthreads();
    l = scrf[772] + scrf[773] + scrf[774] + scrf[775];
    const float aw = e / l;
    scrf[512 + tid] = aw;
    if (eh == 0) __builtin_nontemporal_store(aw, &out_attn[((size_t)b*T + t)*S + tid]);
    __syncthreads();
    // v[n-half] from REGISTERS (ev): wave w covers 64 s rows (2 per iter)
    {
      float a[8] = {0,0,0,0,0,0,0,0};
      const int cc = lane & 31, par = lane >> 5;
#pragma unroll
      for (int i2 = 0; i2 < 32; ++i2){
        const int srow = w*64 + i2*2 + par;
        const float wgt = scrf[512 + srow];
        Ubf u8; u8.v = ev[i2];
        float f0,f1,f2,f3,f4,f5,f6,f7;
        unp2(u8.u[0],f0,f1); unp2(u8.u[1],f2,f3); unp2(u8.u[2],f4,f5); unp2(u8.u[3],f6,f7);
        a[0]+=wgt*f0; a[1]+=wgt*f1; a[2]+=wgt*f2; a[3]+=wgt*f3;
        a[4]+=wgt*f4; a[5]+=wgt*f5; a[6]+=wgt*f6; a[7]+=wgt*f7;
      }
#pragma unroll
      for (int j2 = 0; j2 < 8; ++j2) a[j2] += __shfl_xor(a[j2], 32, 64);
      if (par == 0){
#pragma unroll
        for (int j2 = 0; j2 < 8; ++j2) scrf[784 + w*256 + cc*8 + j2] = a[j2];
      }
    }
    __syncthreads();
    // feed[b, eh*256 + tid] = tanh(hw + v)
    {
      const float v = scrf[784 + tid] + scrf[784 + 256 + tid]
                    + scrf[784 + 512 + tid] + scrf[784 + 768 + tid];
      scrf[1808 + tid] = tanhf(hw + v);
    }
    __syncthreads();
    if (tid < 128){
      const int n2 = tid*2;
      stc4(&feed[(size_t)b*512 + eh*256 + n2],
           (unsigned)f2bf(scrf[1808 + n2]) | ((unsigned)f2bf(scrf[1808 + n2 + 1]) << 16));
    }
    bar_arr(cl(cnts, F_OFF + bid));   // 1 arrival/line/step
  }
  // final out-projection (feed_255)
  if (j & 1){
    barw(Fset, 256u, 31);
    const int d = tid >> 6, kk = lane;
    const unsigned short* fp = feed + (size_t)b*512 + kk*8;
    F16x8 u; u.q[0] = ldc8(fp); u.q[1] = ldc8(fp + 4);
    const float* wp = Wout + d*512 + kk*8;
    float p = 0.f;
#pragma unroll
    for (int j2 = 0; j2 < 8; ++j2) p += bf2f(u.s[j2]) * wp[j2];
#pragma unroll
    for (int off = 32; off > 0; off >>= 1) p += __shfl_down(p, off, 64);
    if (kk == 0){
      const float v = p + bout[d];
      out_main[((size_t)b*T + 255)*4 + d] = (d < 3) ? tanhf(v) : fmaxf(v, 0.f);
    }
  }
}

// ---------------- setup / builder kernels ----------------
__global__ __launch_bounds__(256) void k_build_encw(
  const float* __restrict__ WihF, const float* __restrict__ WhhF,
  const float* __restrict__ WihB, const float* __restrict__ WhhB,
  unsigned short* WF, unsigned short* WB)
{
  const int idx = blockIdx.x*256 + threadIdx.x;     // 2*1024*512
  const int dir = idx >> 19;
  const int i2 = idx & 524287;
  const int row = i2 >> 9, col = i2 & 511;
  const int j = row >> 2, g = row & 3;
  const int orig = g*256 + j;
  const float* Wih = dir ? WihB : WihF;
  const float* Whh = dir ? WhhB : WhhF;
  const float v = (col < 256) ? Wih[orig*256 + col] : Whh[orig*256 + (col-256)];
  (dir ? WB : WF)[i2] = f2bf(v);
}

// gates weights: reorder rows (j*4+g), pad cols to 1088, swizzle to frag order
__global__ __launch_bounds__(256) void k_build_decw(
  const float* __restrict__ Wih, const float* __restrict__ Whh, unsigned short* WDx)
{
  const int idx = blockIdx.x*256 + threadIdx.x;
  if (idx >= 2048*1088) return;
  const int row = idx / 1088, col = idx - row*1088;
  const int j = row >> 2, g = row & 3;
  const int orig = g*512 + j;
  float v;
  if (col < 16)        v = Wih[orig*528 + col];          // w_t part
  else if (col < 64)   v = 0.f;                          // pad
  else if (col < 576)  v = Wih[orig*528 + (col - 48)];   // feed part
  else                 v = Whh[orig*512 + (col - 576)];  // h part
  const int ng = row >> 4, l16 = row & 15;
  const int ks = col >> 5, qdd = (col >> 3) & 3, jj = col & 7;
  WDx[(((size_t)ng*34 + ks)*64 + qdd*16 + l16)*8 + jj] = f2bf(v);
}

// h-part of W_ctx packed for GEMV: WhP[(k>>3)*512 + n][k&7] = Wctx[n, k]
__global__ __launch_bounds__(256) void k_build_whp(
  const float* __restrict__ Wctx, unsigned short* WhP)
{
  const int idx = blockIdx.x*256 + threadIdx.x;     // 512*512
  const int k = idx >> 9, n = idx & 511;
  WhP[(((size_t)(k >> 3)*512 + n) << 3) + (k & 7)] = f2bf(Wctx[(size_t)n*1024 + k]);
}

// ctx-part of W_ctx in B-frag order for encW GEMM: n = dec-out, k = e
__global__ __launch_bounds__(256) void k_build_wcp(
  const float* __restrict__ Wctx, unsigned short* WCP)
{
  const int idx = blockIdx.x*256 + threadIdx.x;     // 512*512
  const int n = idx >> 9, e = idx & 511;
  const int qn = n >> 4, l16 = n & 15;
  const int ks = e >> 5, qdd = (e >> 3) & 3, jj = e & 7;
  WCP[(((size_t)qn*16 + ks)*64 + qdd*16 + l16)*8 + jj] = f2bf(Wctx[(size_t)n*1024 + 512 + e]);
}

// W_src in B-frag order for proj GEMM: n = d (512), k = e (512)
__global__ __launch_bounds__(256) void k_build_wsp(
  const float* __restrict__ Wsrc, unsigned short* WSP)
{
  const int idx = blockIdx.x*256 + threadIdx.x;     // 512*512
  const int d = idx >> 9, e = idx & 511;
  const int qn = d >> 4, l16 = d & 15;
  const int ks = e >> 5, qdd = (e >> 3) & 3, jj = e & 7;
  WSP[(((size_t)qn*16 + ks)*64 + qdd*16 + l16)*8 + jj] = f2bf(Wsrc[(size_t)d*512 + e]);
}

__global__ __launch_bounds__(256) void k_build_bias(
  const float* __restrict__ ebF, const float* __restrict__ ebB,
  const float* __restrict__ dB, float* bF, float* bB, float* bD)
{
  const int idx = blockIdx.x*256 + threadIdx.x;     // 4096
  if (idx < 1024) bF[idx] = ebF[(idx&3)*256 + (idx>>2)];
  else if (idx < 2048){ const int i = idx-1024; bB[i] = ebB[(i&3)*256 + (i>>2)]; }
  else { const int i = idx-2048; bD[i] = dB[(i&3)*512 + (i>>2)]; }
}

__global__ __launch_bounds__(256) void k_embed(
  const int* __restrict__ in_seq, const float* __restrict__ table, unsigned short* emb)
{
  const int idx = blockIdx.x*256 + threadIdx.x;     // S*B*256, layout (S,B,E)
  const int e = idx & 255, b = (idx >> 8) & 127, s = idx >> 15;
  const int tok = in_seq[b*S + s];
  emb[idx] = f2bf(table[(size_t)tok*256 + e]);
}

__global__ __launch_bounds__(256) void k_win(
  const float* __restrict__ tgt, unsigned short* win)
{
  const int idx = blockIdx.x*256 + threadIdx.x;     // T*B*64, layout (T,B,64)
  const int c = idx & 63, b = (idx >> 6) & 127, t = idx >> 13;
  float v = 0.f;
  if (c < 16){
    const int k = c >> 2, jj = c & 3;
    const int ts = t + k - 4;
    if (ts >= 0) v = tgt[((size_t)b*T + ts)*4 + jj];
  }
  win[idx] = f2bf(v);
}

// ---------------------------------------------------------------------------
extern "C" void kernel_launch(void* const* d_in, const int* in_sizes, int n_in,
                              void* d_out, int out_size, void* d_ws, size_t ws_size,
                              hipStream_t stream)
{
  const int*   in_seq    = (const int*)d_in[0];
  const float* tgt       = (const float*)d_in[1];
  // d_in[2] = lengths (unused by reference)
  const float* embedding = (const float*)d_in[3];
  const float* eWihF = (const float*)d_in[4];
  const float* eWhhF = (const float*)d_in[5];
  const float* ebF   = (const float*)d_in[6];
  const float* eWihB = (const float*)d_in[7];
  const float* eWhhB = (const float*)d_in[8];
  const float* ebB   = (const float*)d_in[9];
  const float* dWih  = (const float*)d_in[10];
  const float* dWhh  = (const float*)d_in[11];
  const float* dB    = (const float*)d_in[12];
  const float* Wsrc  = (const float*)d_in[13];
  const float* Wctx  = (const float*)d_in[14];
  const float* Wout  = (const float*)d_in[15];
  const float* bout  = (const float*)d_in[16];

  char* ws = (char*)d_ws;
  size_t off = 0;
  auto al = [&](size_t bytes)->char*{
    char* p = ws + off; off += (bytes + 255) & ~(size_t)255; return p; };

  // --- state region (zeroed every launch with one memset) ---
  char* stateBase = ws;
  unsigned short* hEnc = (unsigned short*)al(262144);  // [2][2][128][256]
  unsigned short* hdec = (unsigned short*)al(262144);  // [2][128][512]
  unsigned short* feed = (unsigned short*)al(131072);  // [128][512]
  unsigned*       cnts = (unsigned*)al(90112);         // 672 counter lines
  const size_t stateBytes = off;

  // --- persistent-per-launch scratch (fully rewritten each launch) ---
  unsigned short* emb    = (unsigned short*)al(16777216);  // (S,B,256) bf16
  unsigned short* win    = (unsigned short*)al(4194304);   // (T,B,64) bf16
  unsigned short* encOut = (unsigned short*)al(33554432);  // (B,S,512) bf16
  unsigned short* proj   = (unsigned short*)al(33554432);  // (B,2,S,256) bf16
  unsigned short* encWq  = (unsigned short*)al(33554432);  // (B,2,S,256) bf16
  unsigned short* WF     = (unsigned short*)al(1048576);   // 1024x512
  unsigned short* WB     = (unsigned short*)al(1048576);
  unsigned short* WDx    = (unsigned short*)al(4456448);   // swizzled 2048x1088
  unsigned short* WhP    = (unsigned short*)al(524288);    // packed 512x512 (GEMV)
  unsigned short* WCP    = (unsigned short*)al(524288);    // swizzled 512x512 (encW B)
  unsigned short* WSP    = (unsigned short*)al(524288);    // swizzled 512x512 (proj B)
  float*          scp    = (float*)al(262144);             // [128][2][256]
  float* bFr = (float*)al(4096);
  float* bBr = (float*)al(4096);
  float* bDr = (float*)al(8192);
  (void)ws_size; (void)in_sizes; (void)n_in; (void)out_size;

  float* out_main = (float*)d_out;
  float* out_attn = out_main + (size_t)B*T*DOF;

  const dim3 blk(256);
  k_build_encw <<<4096,  blk, 0, stream>>>(eWihF, eWhhF, eWihB, eWhhB, WF, WB);
  k_build_decw <<<8704,  blk, 0, stream>>>(dWih, dWhh, WDx);
  k_build_whp  <<<1024,  blk, 0, stream>>>(Wctx, WhP);
  k_build_wcp  <<<1024,  blk, 0, stream>>>(Wctx, WCP);
  k_build_wsp  <<<1024,  blk, 0, stream>>>(Wsrc, WSP);
  k_build_bias <<<16,    blk, 0, stream>>>(ebF, ebB, dB, bFr, bBr, bDr);
  k_embed      <<<32768, blk, 0, stream>>>(in_seq, embedding, emb);
  k_win        <<<8192,  blk, 0, stream>>>(tgt, win);
  hipMemsetAsync(stateBase, 0, stateBytes, stream);

  // persistent encoder: 256 steps internally
  k_encoder<<<256, blk, 0, stream>>>(emb, WF, WB, bFr, bBr, hEnc, encOut,
                                     cnts + (size_t)ENC_OFF*CLINE);

  // one-shot proj + encW GEMMs (step-invariant attention matrices)
  k_proj<<<4096, blk, 0, stream>>>(encOut, WSP, WCP, proj, encWq);

  // persistent decoder: 256 steps, 8 INDEPENDENT groups of 32 blocks
  // (group-local barriers, fan-in 32, zero cross-group sync)
  k_decoder<<<256, blk, 0, stream>>>(win, WDx, bDr, WhP, proj, encWq, in_seq,
                                     Wout, bout, hdec, feed, scp,
                                     out_main, out_attn, cnts);
}